// Round 2
// baseline (3148.555 us; speedup 1.0000x reference)
//
#include <hip/hip_runtime.h>
#include <hip/hip_bf16.h>

// Problem constants
#define B_   2
#define T_   2048
#define M_   2048
#define D_   384
#define H_   4
#define DH_  96
#define NM_  8
#define DF_  1536
#define R_   16
#define NR_  4096   // B*T = B*M rows

// ---------------- LayerNorm: one block (384 threads) per row ----------------
__global__ __launch_bounds__(384)
void ln_kernel(const float* __restrict__ x, const float* __restrict__ g,
               const float* __restrict__ b, float* __restrict__ out) {
    __shared__ float sm[8];
    int row = blockIdx.x;
    int t = threadIdx.x;                  // 0..383
    float v = x[(long)row * D_ + t];

    float s = v;
    for (int o = 32; o > 0; o >>= 1) s += __shfl_down(s, o);
    if ((t & 63) == 0) sm[t >> 6] = s;
    __syncthreads();
    float mu = 0.f;
    for (int i = 0; i < 6; i++) mu += sm[i];
    mu *= (1.f / D_);
    __syncthreads();

    float d = v - mu;
    s = d * d;
    for (int o = 32; o > 0; o >>= 1) s += __shfl_down(s, o);
    if ((t & 63) == 0) sm[t >> 6] = s;
    __syncthreads();
    float var = 0.f;
    for (int i = 0; i < 6; i++) var += sm[i];
    var *= (1.f / D_);

    float r = rsqrtf(var + 1e-5f);
    out[(long)row * D_ + t] = d * r * g[t] + b[t];
}

// ---------------- Gates: sigmoid(motif_ctrl @ gW^T + gb), [B,H] ----------------
__global__ void gates_kernel(const float* __restrict__ mc, const float* __restrict__ gW,
                             const float* __restrict__ gb, float* __restrict__ gates) {
    int i = threadIdx.x;
    if (i < B_ * H_) {
        int b = i / H_, h = i % H_;
        float s = gb[h];
        for (int n = 0; n < NM_; n++)
            s += mc[b * NM_ + n] * gW[h * NM_ + n];
        gates[i] = 1.f / (1.f + __expf(-s));
    }
}

// ---------------- GEMM: C[NR,NC] = act(A[NR,K] @ W[NC,K]^T + bias) + res ----------------
// 64x64 tile, BK=16, 256 threads, 4x4 per thread. ACT: 0=none, 1=exact gelu.
template<int ACT>
__global__ __launch_bounds__(256)
void gemm_kernel(const float* __restrict__ A, const float* __restrict__ W,
                 const float* __restrict__ bias, const float* __restrict__ res,
                 float* __restrict__ C, int NR, int NC, int K,
                 const int* __restrict__ aidx, int astride) {
    if (aidx) W += (long)(*aidx) * astride;
    __shared__ float As[16][65];
    __shared__ float Ws[16][65];
    int bm = blockIdx.y * 64, bn = blockIdx.x * 64;
    int tx = threadIdx.x & 15, ty = threadIdx.x >> 4;
    float acc[4][4] = {};

    for (int k0 = 0; k0 < K; k0 += 16) {
        for (int l = threadIdx.x; l < 1024; l += 256) {
            int r_ = l >> 4, kk = l & 15;
            As[kk][r_] = A[(long)(bm + r_) * K + k0 + kk];
            Ws[kk][r_] = (bn + r_ < NC) ? W[(long)(bn + r_) * K + k0 + kk] : 0.f;
        }
        __syncthreads();
        #pragma unroll
        for (int kk = 0; kk < 16; kk++) {
            float a[4], w[4];
            #pragma unroll
            for (int i = 0; i < 4; i++) a[i] = As[kk][ty * 4 + i];
            #pragma unroll
            for (int j = 0; j < 4; j++) w[j] = Ws[kk][tx * 4 + j];
            #pragma unroll
            for (int i = 0; i < 4; i++)
                #pragma unroll
                for (int j = 0; j < 4; j++)
                    acc[i][j] = fmaf(a[i], w[j], acc[i][j]);
        }
        __syncthreads();
    }

    #pragma unroll
    for (int i = 0; i < 4; i++) {
        int m = bm + ty * 4 + i;
        #pragma unroll
        for (int j = 0; j < 4; j++) {
            int n = bn + tx * 4 + j;
            if (n < NC) {
                float v = acc[i][j];
                if (bias) v += bias[n];
                if (ACT == 1) v = 0.5f * v * (1.f + erff(v * 0.70710678118654752f));
                if (res) v += res[(long)m * NC + n];
                C[(long)m * NC + n] = v;
            }
        }
    }
}

// ---------------- Attention: online softmax, 32 Q-rows per block ----------------
// Q,K,V stored as [B, rows, D] with head h at cols [h*DH, (h+1)*DH).
// Z[b,t,h,:] = gate(b,h) * softmax(Qs @ K^T) @ V   (Q pre-scaled by 1/sqrt(DH))
__global__ __launch_bounds__(256)
void attn_kernel(const float* __restrict__ Qb, const float* __restrict__ Kb,
                 const float* __restrict__ Vb, const float* __restrict__ gates,
                 float* __restrict__ Z, int nkeys) {
    __shared__ float Qs[32][DH_ + 1];
    __shared__ float KVs[32][DH_ + 1];
    __shared__ float Ss[32][33];

    int bh = blockIdx.y, b = bh >> 2, h = bh & 3;
    int t0 = blockIdx.x * 32;
    const float scale = 0.10206207261596575f;  // 1/sqrt(96)

    const float* Qbase = Qb + ((long)b * T_ + t0) * D_ + h * DH_;
    const float* Kbase = Kb + ((long)b * nkeys) * D_ + h * DH_;
    const float* Vbase = Vb + ((long)b * nkeys) * D_ + h * DH_;

    for (int l = threadIdx.x; l < 32 * DH_; l += 256) {
        int r_ = l / DH_, c = l - r_ * DH_;
        Qs[r_][c] = Qbase[(long)r_ * D_ + c] * scale;
    }

    int r  = threadIdx.x >> 3;         // 0..31 : Q row
    int c0 = (threadIdx.x & 7) * 12;   // 12 output cols per thread
    float o[12];
    #pragma unroll
    for (int i = 0; i < 12; i++) o[i] = 0.f;
    float mrow = -3e38f, lrow = 0.f;

    for (int j0 = 0; j0 < nkeys; j0 += 32) {
        __syncthreads();  // protect KVs (V of prev iter) + Qs on first iter
        for (int l = threadIdx.x; l < 32 * DH_; l += 256) {
            int r_ = l / DH_, c = l - r_ * DH_;
            KVs[r_][c] = Kbase[(long)(j0 + r_) * D_ + c];
        }
        __syncthreads();
        // scores: 32x32, 4 per thread
        for (int l = threadIdx.x; l < 1024; l += 256) {
            int rr = l >> 5, jj = l & 31;
            float s = 0.f;
            #pragma unroll
            for (int d = 0; d < DH_; d++) s = fmaf(Qs[rr][d], KVs[jj][d], s);
            Ss[rr][jj] = s;
        }
        __syncthreads();
        // load V into KVs (Ss already holds scores)
        for (int l = threadIdx.x; l < 32 * DH_; l += 256) {
            int r_ = l / DH_, c = l - r_ * DH_;
            KVs[r_][c] = Vbase[(long)(j0 + r_) * D_ + c];
        }
        // online softmax row stats (each of 8 threads per row duplicates)
        float cmax = -3e38f;
        #pragma unroll
        for (int j = 0; j < 32; j++) cmax = fmaxf(cmax, Ss[r][j]);
        float mnew = fmaxf(mrow, cmax);
        float alpha = __expf(mrow - mnew);
        float p[32], ps = 0.f;
        #pragma unroll
        for (int j = 0; j < 32; j++) { p[j] = __expf(Ss[r][j] - mnew); ps += p[j]; }
        lrow = lrow * alpha + ps;
        mrow = mnew;
        #pragma unroll
        for (int i = 0; i < 12; i++) o[i] *= alpha;
        __syncthreads();  // V ready
        #pragma unroll
        for (int j = 0; j < 32; j++) {
            float pj = p[j];
            #pragma unroll
            for (int i = 0; i < 12; i++) o[i] = fmaf(pj, KVs[j][c0 + i], o[i]);
        }
    }

    float gate = gates ? gates[bh] : 1.f;
    float inv = gate / lrow;
    float* Zbase = Z + ((long)b * T_ + t0) * D_ + h * DH_;
    #pragma unroll
    for (int i = 0; i < 12; i++) Zbase[(long)r * D_ + c0 + i] = o[i] * inv;
}

// ---------------- Launch ----------------
extern "C" void kernel_launch(void* const* d_in, const int* in_sizes, int n_in,
                              void* d_out, int out_size, void* d_ws, size_t ws_size,
                              hipStream_t stream) {
    const float* x    = (const float*)d_in[0];
    const float* mem  = (const float*)d_in[1];
    const float* mc   = (const float*)d_in[2];
    const int*   aidx = (const int*)d_in[3];
    const float* cWq = (const float*)d_in[4],  *cbq = (const float*)d_in[5];
    const float* cWk = (const float*)d_in[6],  *cbk = (const float*)d_in[7];
    const float* cWv = (const float*)d_in[8],  *cbv = (const float*)d_in[9];
    const float* cWo = (const float*)d_in[10], *cbo = (const float*)d_in[11];
    const float* sWq = (const float*)d_in[12], *sbq = (const float*)d_in[13];
    const float* sWk = (const float*)d_in[14], *sbk = (const float*)d_in[15];
    const float* sWv = (const float*)d_in[16], *sbv = (const float*)d_in[17];
    const float* sWo = (const float*)d_in[18], *sbo = (const float*)d_in[19];
    const float* gW  = (const float*)d_in[20], *gb  = (const float*)d_in[21];
    const float* f1W = (const float*)d_in[22], *f1b = (const float*)d_in[23];
    const float* f2W = (const float*)d_in[24], *f2b = (const float*)d_in[25];
    const float* adA = (const float*)d_in[26], *adB = (const float*)d_in[27];
    const float* ln1g = (const float*)d_in[28], *ln1b = (const float*)d_in[29];
    const float* ln2g = (const float*)d_in[30], *ln2b = (const float*)d_in[31];
    const float* ln3g = (const float*)d_in[32], *ln3b = (const float*)d_in[33];

    float* ws = (float*)d_ws;
    size_t S1 = (size_t)NR_ * D_;
    float* bufH  = ws;
    float* bufQ  = bufH  + S1;
    float* bufK  = bufQ  + S1;
    float* bufV  = bufK  + S1;
    float* bufZ  = bufV  + S1;
    float* bufX1 = bufZ  + S1;
    float* bufX2 = bufX1 + S1;
    float* bufF  = bufX2 + S1;                    // [NR, DF]
    float* bufT  = bufF  + (size_t)NR_ * DF_;     // [NR, R]
    float* gbuf  = bufT  + (size_t)NR_ * R_;      // [B*H]

    const float* nf = nullptr;
    dim3 gD(6, 64), gF(24, 64), gL(1, 64);

    // --- cross-attention ---
    ln_kernel<<<NR_, 384, 0, stream>>>(x, ln1g, ln1b, bufH);
    gemm_kernel<0><<<gD, 256, 0, stream>>>(bufH, cWq, cbq, nf, bufQ, NR_, D_, D_, nullptr, 0);
    gemm_kernel<0><<<gD, 256, 0, stream>>>(mem,  cWk, cbk, nf, bufK, NR_, D_, D_, nullptr, 0);
    gemm_kernel<0><<<gD, 256, 0, stream>>>(mem,  cWv, cbv, nf, bufV, NR_, D_, D_, nullptr, 0);
    attn_kernel<<<dim3(64, 8), 256, 0, stream>>>(bufQ, bufK, bufV, nullptr, bufZ, M_);
    gemm_kernel<0><<<gD, 256, 0, stream>>>(bufZ, cWo, cbo, x, bufX1, NR_, D_, D_, nullptr, 0);

    // --- motif-gated self-attention ---
    ln_kernel<<<NR_, 384, 0, stream>>>(bufX1, ln2g, ln2b, bufH);
    gates_kernel<<<1, 64, 0, stream>>>(mc, gW, gb, gbuf);
    gemm_kernel<0><<<gD, 256, 0, stream>>>(bufH, sWq, sbq, nf, bufQ, NR_, D_, D_, nullptr, 0);
    gemm_kernel<0><<<gD, 256, 0, stream>>>(bufH, sWk, sbk, nf, bufK, NR_, D_, D_, nullptr, 0);
    gemm_kernel<0><<<gD, 256, 0, stream>>>(bufH, sWv, sbv, nf, bufV, NR_, D_, D_, nullptr, 0);
    attn_kernel<<<dim3(64, 8), 256, 0, stream>>>(bufQ, bufK, bufV, gbuf, bufZ, T_);
    gemm_kernel<0><<<gD, 256, 0, stream>>>(bufZ, sWo, sbo, bufX1, bufX2, NR_, D_, D_, nullptr, 0);

    // --- FFN + LoRA ---
    ln_kernel<<<NR_, 384, 0, stream>>>(bufX2, ln3g, ln3b, bufH);
    gemm_kernel<1><<<gF, 256, 0, stream>>>(bufH, f1W, f1b, nf, bufF, NR_, DF_, D_, nullptr, 0);
    gemm_kernel<0><<<gL, 256, 0, stream>>>(bufH, adA, nullptr, nf, bufT, NR_, R_, D_, aidx, R_ * D_);
    gemm_kernel<0><<<gD, 256, 0, stream>>>(bufF, f2W, f2b, bufX2, bufX1, NR_, D_, DF_, nullptr, 0);
    gemm_kernel<0><<<gD, 256, 0, stream>>>(bufT, adB, nullptr, bufX1, (float*)d_out, NR_, D_, R_, aidx, D_ * R_);
}

// Round 4
// 448.426 us; speedup vs baseline: 7.0214x; 7.0214x over previous
//
#include <hip/hip_runtime.h>
#include <hip/hip_bf16.h>
#include <math.h>

// Problem constants
#define B_   2
#define T_   2048
#define M_   2048
#define D_   384
#define H_   4
#define DH_  96
#define NM_  8
#define DF_  1536
#define R_   16
#define NR_  4096   // B*T = B*M rows

typedef unsigned short u16;
typedef u16    u16x8  __attribute__((ext_vector_type(8)));
typedef __bf16 bf16x8 __attribute__((ext_vector_type(8)));
typedef float  f32x4  __attribute__((ext_vector_type(4)));

union V8 { u16x8 u; bf16x8 b; };
__device__ __forceinline__ bf16x8 as_bf(u16x8 x) { V8 v; v.u = x; return v.b; }

__device__ __forceinline__ u16 f2bf(float f) {
    unsigned u = __float_as_uint(f);
    unsigned r = (u + 0x7fffu + ((u >> 16) & 1u)) >> 16;
    return (u16)r;
}

// ---------------- fp32 -> bf16 converters ----------------
__global__ void cvt8_kernel(const float* s0, const float* s1, const float* s2, const float* s3,
                            const float* s4, const float* s5, const float* s6, const float* s7,
                            u16* d0, u16* d1, u16* d2, u16* d3,
                            u16* d4, u16* d5, u16* d6, u16* d7, int n) {
    const float* s; u16* d;
    switch (blockIdx.y) {
        case 0: s = s0; d = d0; break;  case 1: s = s1; d = d1; break;
        case 2: s = s2; d = d2; break;  case 3: s = s3; d = d3; break;
        case 4: s = s4; d = d4; break;  case 5: s = s5; d = d5; break;
        case 6: s = s6; d = d6; break;  default: s = s7; d = d7; break;
    }
    for (int i = blockIdx.x * blockDim.x + threadIdx.x; i < n; i += gridDim.x * blockDim.x)
        d[i] = f2bf(s[i]);
}

__global__ void cvt2_kernel(const float* s0, const float* s1, u16* d0, u16* d1, int n) {
    const float* s = blockIdx.y ? s1 : s0;
    u16* d = blockIdx.y ? d1 : d0;
    for (int i = blockIdx.x * blockDim.x + threadIdx.x; i < n; i += gridDim.x * blockDim.x)
        d[i] = f2bf(s[i]);
}

__global__ void cvt1_kernel(const float* s, u16* d, int n) {
    for (int i = blockIdx.x * blockDim.x + threadIdx.x; i < n; i += gridDim.x * blockDim.x)
        d[i] = f2bf(s[i]);
}

// pack biases: bkv_c[768] = [cbk|cbv]; bqkv_s[1152] = [sbq|sbk|sbv]
__global__ void pack_bias_kernel(const float* cbk, const float* cbv,
                                 const float* sbq, const float* sbk, const float* sbv,
                                 float* bkv_c, float* bqkv_s) {
    int i = blockIdx.x * blockDim.x + threadIdx.x;
    if (i < 768) bkv_c[i] = (i < 384) ? cbk[i] : cbv[i - 384];
    else if (i < 1920) {
        int j = i - 768;
        bqkv_s[j] = (j < 384) ? sbq[j] : (j < 768 ? sbk[j - 384] : sbv[j - 768]);
    }
}

// ---------------- LayerNorm: fp32 in, bf16 out ----------------
__global__ __launch_bounds__(384)
void ln_kernel(const float* __restrict__ x, const float* __restrict__ g,
               const float* __restrict__ b, u16* __restrict__ out) {
    __shared__ float sm[8];
    int row = blockIdx.x;
    int t = threadIdx.x;
    float v = x[(long)row * D_ + t];

    float s = v;
    for (int o = 32; o > 0; o >>= 1) s += __shfl_down(s, o);
    if ((t & 63) == 0) sm[t >> 6] = s;
    __syncthreads();
    float mu = 0.f;
    for (int i = 0; i < 6; i++) mu += sm[i];
    mu *= (1.f / D_);
    __syncthreads();

    float d = v - mu;
    s = d * d;
    for (int o = 32; o > 0; o >>= 1) s += __shfl_down(s, o);
    if ((t & 63) == 0) sm[t >> 6] = s;
    __syncthreads();
    float var = 0.f;
    for (int i = 0; i < 6; i++) var += sm[i];
    var *= (1.f / D_);

    float r = rsqrtf(var + 1e-5f);
    out[(long)row * D_ + t] = f2bf(d * r * g[t] + b[t]);
}

// ---------------- Gates: sigmoid(motif_ctrl @ gW^T + gb), [B,H] fp32 ----------------
__global__ void gates_kernel(const float* __restrict__ mc, const float* __restrict__ gW,
                             const float* __restrict__ gb, float* __restrict__ gates) {
    int i = threadIdx.x;
    if (i < B_ * H_) {
        int b = i / H_, h = i % H_;
        float s = gb[h];
        for (int n = 0; n < NM_; n++)
            s += mc[b * NM_ + n] * gW[h * NM_ + n];
        gates[i] = 1.f / (1.f + __expf(-s));
    }
}

// ---------------- MFMA GEMM: C[NR,NC] = act(A[NR,K] @ W[NC,K]^T + bias) + res ----------------
// 64x64 block tile, BK=32, 4 waves each computing 32x32 (2x2 MFMA tiles of 16x16x32).
// LDS is frag-ordered: [tile16][kquad][row][8] so frag ds_read_b128 is lane-sequential.
template<int ACT, bool OBF>
__global__ __launch_bounds__(256)
void gemm_mfma(const u16* __restrict__ A, const u16* __restrict__ W,
               const float* __restrict__ bias, const float* __restrict__ res,
               void* __restrict__ Cout, int NR, int NC, int K,
               const int* __restrict__ aidx, int astride) {
    if (aidx) W += (long)aidx[0] * astride;
    __shared__ __align__(16) u16 As[2048];   // 64x32 bf16, frag-ordered
    __shared__ __align__(16) u16 Ws[2048];
    int tid = threadIdx.x;
    int w = tid >> 6, lane = tid & 63;
    int bm = blockIdx.y * 64, bn = blockIdx.x * 64;
    int mt0 = (w & 1) * 2, nt0 = (w >> 1) * 2;

    int srow = ((tid >> 6) << 4) + (tid & 15);   // staging row 0..63
    int kq8  = ((tid >> 4) & 3) * 8;             // staging k-offset 0..24
    const u16* Ag = A + (long)(bm + srow) * K + kq8;
    int wrow = bn + srow;
    const u16* Wg = W + (long)wrow * K + kq8;
    bool wok = wrow < NC;

    f32x4 acc[2][2];
    #pragma unroll
    for (int i = 0; i < 2; i++)
        #pragma unroll
        for (int j = 0; j < 2; j++) acc[i][j] = (f32x4){0.f, 0.f, 0.f, 0.f};

    for (int k0 = 0; k0 < K; k0 += 32) {
        u16x8 av = {0, 0, 0, 0, 0, 0, 0, 0};
        u16x8 wv = {0, 0, 0, 0, 0, 0, 0, 0};
        bool kok = (k0 + kq8) < K;
        if (kok) av = *(const u16x8*)(Ag + k0);
        if (kok && wok) wv = *(const u16x8*)(Wg + k0);
        __syncthreads();
        *(u16x8*)(As + tid * 8) = av;
        *(u16x8*)(Ws + tid * 8) = wv;
        __syncthreads();
        u16x8 af[2], bfv[2];
        #pragma unroll
        for (int i = 0; i < 2; i++) {
            af[i]  = *(const u16x8*)(As + (mt0 + i) * 512 + lane * 8);
            bfv[i] = *(const u16x8*)(Ws + (nt0 + i) * 512 + lane * 8);
        }
        #pragma unroll
        for (int i = 0; i < 2; i++)
            #pragma unroll
            for (int j = 0; j < 2; j++)
                acc[i][j] = __builtin_amdgcn_mfma_f32_16x16x32_bf16(
                    as_bf(af[i]), as_bf(bfv[j]), acc[i][j], 0, 0, 0);
    }

    int quad = lane >> 4, l15 = lane & 15;
    #pragma unroll
    for (int mi = 0; mi < 2; mi++) {
        #pragma unroll
        for (int nj = 0; nj < 2; nj++) {
            int col = bn + (nt0 + nj) * 16 + l15;
            if (col < NC) {
                float bv = bias ? bias[col] : 0.f;
                int rowb = bm + (mt0 + mi) * 16 + quad * 4;
                #pragma unroll
                for (int r = 0; r < 4; r++) {
                    float v = acc[mi][nj][r] + bv;
                    if (ACT == 1) v = 0.5f * v * (1.f + erff(v * 0.70710678118654752f));
                    long idx = (long)(rowb + r) * NC + col;
                    if (res) v += res[idx];
                    if (OBF) ((u16*)Cout)[idx] = f2bf(v);
                    else     ((float*)Cout)[idx] = v;
                }
            }
        }
    }
}

// ---------------- V transpose: [B,2048 rows, istride] cols(384 slice) -> Vt [B][384][2048] ----------------
__global__ __launch_bounds__(256)
void transp_kernel(const u16* __restrict__ in, int istride, u16* __restrict__ out) {
    __shared__ __align__(16) u16 tile[64 * 72];
    int b = blockIdx.z;
    int r0 = blockIdx.x * 64;   // key rows
    int c0 = blockIdx.y * 64;   // V cols
    const u16* ib = in + (long)(b * 2048 + r0) * istride + c0;
    #pragma unroll
    for (int it = 0; it < 2; it++) {
        int c = threadIdx.x + it * 256;
        int i = c >> 3, jq = c & 7;
        *(u16x8*)&tile[i * 72 + jq * 8] = *(const u16x8*)(ib + (long)i * istride + jq * 8);
    }
    __syncthreads();
    u16* ob = out + (long)(b * 384 + c0) * 2048 + r0;
    #pragma unroll
    for (int it = 0; it < 2; it++) {
        int c = threadIdx.x + it * 256;
        int i2 = c >> 3, jq = c & 7;
        u16x8 v;
        #pragma unroll
        for (int e = 0; e < 8; e++) v[e] = tile[(jq * 8 + e) * 72 + i2];
        *(u16x8*)(ob + (long)i2 * 2048 + jq * 8) = v;
    }
}

// ---------------- Flash attention, bf16 MFMA ----------------
// grid (32, 8): 64 Q-rows per block (16/wave), one (b,h) per y.
// Q: [B*2048, qs] with head at col h*96; K same w/ ks; Vt: [B][384][2048].
// Z out: [B*2048, 384] bf16, scaled by gate/l.
__global__ __launch_bounds__(256)
void attn_mfma(const u16* __restrict__ Qg, int qs,
               const u16* __restrict__ Kg, int ks,
               const u16* __restrict__ Vt, const float* __restrict__ gates,
               u16* __restrict__ Z) {
    __shared__ __align__(16) u16 Ks[6144];        // 64 keys x 96 dh, frag-ordered [ksub][kstep][quad][row][8]
    __shared__ __align__(16) u16 Vs[96 * 72];     // V^T chunk: [dh][64 keys] padded to 72
    __shared__ __align__(16) u16 Ps[4 * 1088];    // per-wave P, A-frag-ordered w/ 272B quad stride
    const float SCALE = 0.10206207261596575f;     // 1/sqrt(96)

    int tid = threadIdx.x, wv = tid >> 6, lane = tid & 63;
    int l15 = lane & 15, quad = lane >> 4;
    int bh = blockIdx.y, b = bh >> 2, h = bh & 3;
    int q0 = blockIdx.x * 64 + wv * 16;

    const u16* Qb = Qg + (long)(b * 2048 + q0) * qs + h * 96;
    const u16* Kb = Kg + (long)(b * 2048) * ks + h * 96;
    const u16* Vb = Vt + (long)(b * 384 + h * 96) * 2048;

    u16x8 qf[3];
    #pragma unroll
    for (int t = 0; t < 3; t++)
        qf[t] = *(const u16x8*)(Qb + (long)l15 * qs + t * 32 + quad * 8);

    f32x4 o[6];
    #pragma unroll
    for (int i = 0; i < 6; i++) o[i] = (f32x4){0.f, 0.f, 0.f, 0.f};
    float mi[4], li[4];
    #pragma unroll
    for (int r = 0; r < 4; r++) { mi[r] = -3e38f; li[r] = 0.f; }
    u16* Pw = Ps + wv * 1088;

    for (int j0 = 0; j0 < 2048; j0 += 64) {
        // prefetch staging into regs
        u16x8 kst[3], vst[3];
        #pragma unroll
        for (int i = 0; i < 3; i++) {
            int c = tid + i * 256;
            int key = c & 63, dhg = c >> 6;
            kst[i] = *(const u16x8*)(Kb + (long)(j0 + key) * ks + dhg * 8);
            int dh = c >> 3, part = c & 7;
            vst[i] = *(const u16x8*)(Vb + (long)dh * 2048 + j0 + part * 8);
        }
        __syncthreads();
        #pragma unroll
        for (int i = 0; i < 3; i++) {
            int c = tid + i * 256;
            int key = c & 63, dhg = c >> 6;
            *(u16x8*)(Ks + (key >> 4) * 1536 + (dhg >> 2) * 512 + (dhg & 3) * 128 + (key & 15) * 8) = kst[i];
            int dh = c >> 3, part = c & 7;
            *(u16x8*)(Vs + dh * 72 + part * 8) = vst[i];
        }
        __syncthreads();

        // scores: 4 key-subtiles x 3 k-steps
        f32x4 sc[4];
        #pragma unroll
        for (int s = 0; s < 4; s++) sc[s] = (f32x4){0.f, 0.f, 0.f, 0.f};
        #pragma unroll
        for (int s = 0; s < 4; s++)
            #pragma unroll
            for (int t = 0; t < 3; t++) {
                u16x8 kf = *(const u16x8*)(Ks + s * 1536 + t * 512 + lane * 8);
                sc[s] = __builtin_amdgcn_mfma_f32_16x16x32_bf16(as_bf(qf[t]), as_bf(kf), sc[s], 0, 0, 0);
            }
        #pragma unroll
        for (int s = 0; s < 4; s++)
            #pragma unroll
            for (int r = 0; r < 4; r++) sc[s][r] *= SCALE;

        // online softmax: rows = quad*4+r, 16 lanes per quad hold 16 keys
        float mc[4];
        #pragma unroll
        for (int r = 0; r < 4; r++)
            mc[r] = fmaxf(fmaxf(sc[0][r], sc[1][r]), fmaxf(sc[2][r], sc[3][r]));
        #pragma unroll
        for (int off = 1; off < 16; off <<= 1)
            #pragma unroll
            for (int r = 0; r < 4; r++) mc[r] = fmaxf(mc[r], __shfl_xor(mc[r], off));
        float alpha[4], rs[4];
        #pragma unroll
        for (int r = 0; r < 4; r++) {
            float mn = fmaxf(mi[r], mc[r]);
            alpha[r] = __expf(mi[r] - mn);
            mi[r] = mn;
            rs[r] = 0.f;
        }
        #pragma unroll
        for (int s = 0; s < 4; s++)
            #pragma unroll
            for (int r = 0; r < 4; r++) {
                float p = __expf(sc[s][r] - mi[r]);
                sc[s][r] = p;
                rs[r] += p;
            }
        #pragma unroll
        for (int off = 1; off < 16; off <<= 1)
            #pragma unroll
            for (int r = 0; r < 4; r++) rs[r] += __shfl_xor(rs[r], off);
        #pragma unroll
        for (int r = 0; r < 4; r++) li[r] = li[r] * alpha[r] + rs[r];
        #pragma unroll
        for (int nt = 0; nt < 6; nt++)
            #pragma unroll
            for (int r = 0; r < 4; r++) o[nt][r] *= alpha[r];

        // write P (C-layout -> A-frag-ordered LDS), per-wave private
        #pragma unroll
        for (int s = 0; s < 4; s++) {
            int base = (s >> 1) * 544 + ((((s & 1) << 1) | (l15 >> 3))) * 136 + (l15 & 7);
            #pragma unroll
            for (int r = 0; r < 4; r++)
                Pw[base + (quad * 4 + r) * 8] = f2bf(sc[s][r]);
        }
        // PV: 2 k-steps (32 keys each) x 6 dh-tiles
        #pragma unroll
        for (int t2 = 0; t2 < 2; t2++) {
            u16x8 pf = *(const u16x8*)(Pw + t2 * 544 + quad * 136 + l15 * 8);
            #pragma unroll
            for (int nt = 0; nt < 6; nt++) {
                u16x8 vf = *(const u16x8*)(Vs + (nt * 16 + l15) * 72 + t2 * 32 + quad * 8);
                o[nt] = __builtin_amdgcn_mfma_f32_16x16x32_bf16(as_bf(pf), as_bf(vf), o[nt], 0, 0, 0);
            }
        }
    }

    float g = gates ? gates[bh] : 1.0f;
    float inv[4];
    #pragma unroll
    for (int r = 0; r < 4; r++) inv[r] = g / li[r];
    u16* Zb = Z + (long)(b * 2048 + q0) * 384 + h * 96;
    #pragma unroll
    for (int nt = 0; nt < 6; nt++)
        #pragma unroll
        for (int r = 0; r < 4; r++)
            Zb[(long)(quad * 4 + r) * 384 + nt * 16 + l15] = f2bf(o[nt][r] * inv[r]);
}

// ---------------- Launch ----------------
extern "C" void kernel_launch(void* const* d_in, const int* in_sizes, int n_in,
                              void* d_out, int out_size, void* d_ws, size_t ws_size,
                              hipStream_t stream) {
    const float* x    = (const float*)d_in[0];
    const float* mem  = (const float*)d_in[1];
    const float* mc   = (const float*)d_in[2];
    const int*   aidx = (const int*)d_in[3];
    const float* cWq = (const float*)d_in[4],  *cbq = (const float*)d_in[5];
    const float* cWk = (const float*)d_in[6],  *cbk = (const float*)d_in[7];
    const float* cWv = (const float*)d_in[8],  *cbv = (const float*)d_in[9];
    const float* cWo = (const float*)d_in[10], *cbo = (const float*)d_in[11];
    const float* sWq = (const float*)d_in[12], *sbq = (const float*)d_in[13];
    const float* sWk = (const float*)d_in[14], *sbk = (const float*)d_in[15];
    const float* sWv = (const float*)d_in[16], *sbv = (const float*)d_in[17];
    const float* sWo = (const float*)d_in[18], *sbo = (const float*)d_in[19];
    const float* gW  = (const float*)d_in[20], *gb  = (const float*)d_in[21];
    const float* f1W = (const float*)d_in[22], *f1b = (const float*)d_in[23];
    const float* f2W = (const float*)d_in[24], *f2b = (const float*)d_in[25];
    const float* adA = (const float*)d_in[26], *adB = (const float*)d_in[27];
    const float* ln1g = (const float*)d_in[28], *ln1b = (const float*)d_in[29];
    const float* ln2g = (const float*)d_in[30], *ln2b = (const float*)d_in[31];
    const float* ln3g = (const float*)d_in[32], *ln3b = (const float*)d_in[33];

    // ---- workspace layout ----
    u16* p = (u16*)d_ws;
    u16* H      = p; p += (size_t)NR_ * 384;
    u16* bufQ   = p; p += (size_t)NR_ * 384;
    u16* bufKV  = p; p += (size_t)NR_ * 768;
    u16* bufQKV = p; p += (size_t)NR_ * 1152;
    u16* Vt     = p; p += (size_t)B_ * 384 * 2048;
    u16* Zb     = p; p += (size_t)NR_ * 384;
    u16* F      = p; p += (size_t)NR_ * 1536;
    u16* Tl     = p; p += (size_t)NR_ * 16;
    u16* memb   = p; p += (size_t)NR_ * 384;
    u16* Wq_c   = p; p += 147456;
    u16* Wkv_c  = p; p += 294912;
    u16* Wco    = p; p += 147456;
    u16* Wqkv_s = p; p += 442368;
    u16* Wso    = p; p += 147456;
    u16* Wf1    = p; p += 589824;
    u16* Wf2    = p; p += 589824;
    u16* WadA   = p; p += 24576;
    u16* WadB   = p; p += 24576;
    float* fp = (float*)p;
    float* X1 = fp;     fp += (size_t)NR_ * 384;
    float* X2 = fp;     fp += (size_t)NR_ * 384;
    float* X3 = fp;     fp += (size_t)NR_ * 384;
    float* bkv_c  = fp; fp += 768;
    float* bqkv_s = fp; fp += 1152;
    float* gbuf   = fp; fp += 8;

    // ---- weight conversions (fp32 -> bf16, with QKV concat) ----
    cvt8_kernel<<<dim3(72, 8), 256, 0, stream>>>(
        cWq, cWk, cWv, cWo, sWq, sWk, sWv, sWo,
        Wq_c, Wkv_c, Wkv_c + 147456, Wco,
        Wqkv_s, Wqkv_s + 147456, Wqkv_s + 294912, Wso, 147456);
    cvt2_kernel<<<dim3(288, 2), 256, 0, stream>>>(f1W, f2W, Wf1, Wf2, 589824);
    cvt2_kernel<<<dim3(12, 2), 256, 0, stream>>>(adA, adB, WadA, WadB, 24576);
    cvt1_kernel<<<768, 256, 0, stream>>>(mem, memb, NR_ * 384);
    pack_bias_kernel<<<2, 1024, 0, stream>>>(cbk, cbv, sbq, sbk, sbv, bkv_c, bqkv_s);
    gates_kernel<<<1, 64, 0, stream>>>(mc, gW, gb, gbuf);

    const float* nf = nullptr;
    // --- cross-attention ---
    ln_kernel<<<NR_, 384, 0, stream>>>(x, ln1g, ln1b, H);
    gemm_mfma<0, true><<<dim3(6, 64), 256, 0, stream>>>(H, Wq_c, cbq, nf, bufQ, NR_, 384, 384, nullptr, 0);
    gemm_mfma<0, true><<<dim3(12, 64), 256, 0, stream>>>(memb, Wkv_c, bkv_c, nf, bufKV, NR_, 768, 384, nullptr, 0);
    transp_kernel<<<dim3(32, 6, 2), 256, 0, stream>>>(bufKV + 384, 768, Vt);
    attn_mfma<<<dim3(32, 8), 256, 0, stream>>>(bufQ, 384, bufKV, 768, Vt, nullptr, Zb);
    gemm_mfma<0, false><<<dim3(6, 64), 256, 0, stream>>>(Zb, Wco, cbo, x, X1, NR_, 384, 384, nullptr, 0);

    // --- motif-gated self-attention ---
    ln_kernel<<<NR_, 384, 0, stream>>>(X1, ln2g, ln2b, H);
    gemm_mfma<0, true><<<dim3(18, 64), 256, 0, stream>>>(H, Wqkv_s, bqkv_s, nf, bufQKV, NR_, 1152, 384, nullptr, 0);
    transp_kernel<<<dim3(32, 6, 2), 256, 0, stream>>>(bufQKV + 768, 1152, Vt);
    attn_mfma<<<dim3(32, 8), 256, 0, stream>>>(bufQKV, 1152, bufQKV + 384, 1152, Vt, gbuf, Zb);
    gemm_mfma<0, false><<<dim3(6, 64), 256, 0, stream>>>(Zb, Wso, sbo, X1, X2, NR_, 384, 384, nullptr, 0);

    // --- FFN + LoRA ---
    ln_kernel<<<NR_, 384, 0, stream>>>(X2, ln3g, ln3b, H);
    gemm_mfma<1, true><<<dim3(24, 64), 256, 0, stream>>>(H, Wf1, f1b, nf, F, NR_, 1536, 384, nullptr, 0);
    gemm_mfma<0, true><<<dim3(1, 64), 256, 0, stream>>>(H, WadA, nullptr, nf, Tl, NR_, 16, 384, aidx, R_ * D_);
    gemm_mfma<0, false><<<dim3(6, 64), 256, 0, stream>>>(F, Wf2, f2b, X2, X3, NR_, 384, 1536, nullptr, 0);
    gemm_mfma<0, false><<<dim3(6, 64), 256, 0, stream>>>(Tl, WadB, nullptr, X3, d_out, NR_, 384, 16, aidx, D_ * R_);
}

// Round 5
// 416.508 us; speedup vs baseline: 7.5594x; 1.0766x over previous
//
#include <hip/hip_runtime.h>
#include <hip/hip_bf16.h>
#include <math.h>

// Problem constants
#define B_   2
#define T_   2048
#define M_   2048
#define D_   384
#define H_   4
#define DH_  96
#define NM_  8
#define DF_  1536
#define R_   16
#define NR_  4096   // B*T = B*M rows

typedef unsigned short u16;
typedef u16    u16x8  __attribute__((ext_vector_type(8)));
typedef u16    u16x4  __attribute__((ext_vector_type(4)));
typedef __bf16 bf16x8 __attribute__((ext_vector_type(8)));
typedef float  f32x4  __attribute__((ext_vector_type(4)));

union V8 { u16x8 u; bf16x8 b; };
__device__ __forceinline__ bf16x8 as_bf(u16x8 x) { V8 v; v.u = x; return v.b; }

__device__ __forceinline__ u16 f2bf(float f) {
    unsigned u = __float_as_uint(f);
    unsigned r = (u + 0x7fffu + ((u >> 16) & 1u)) >> 16;
    return (u16)r;
}

// ---------------- fused setup: all weight fp32->bf16 converts + bias pack + gates ----------------
// grid (96, 14). y = segment.
__global__ __launch_bounds__(256)
void setup_kernel(const float* cWq, const float* cWk, const float* cWv, const float* cWo,
                  const float* sWq, const float* sWk, const float* sWv, const float* sWo,
                  const float* f1W, const float* f2W, const float* adA, const float* adB,
                  const float* mem,
                  u16* Wq_c, u16* Wkv_c, u16* Wco, u16* Wqkv_s, u16* Wso,
                  u16* Wf1, u16* Wf2, u16* WadA, u16* WadB, u16* memb,
                  const float* cbk, const float* cbv,
                  const float* sbq, const float* sbk, const float* sbv,
                  float* bkv_c, float* bqkv_s,
                  const float* mc, const float* gW, const float* gb, float* gates) {
    int seg = blockIdx.y;
    if (seg == 13) {
        // biases + gates (small)
        for (int i = blockIdx.x * 256 + threadIdx.x; i < 1928; i += gridDim.x * 256) {
            if (i < 768) bkv_c[i] = (i < 384) ? cbk[i] : cbv[i - 384];
            else if (i < 1920) {
                int j = i - 768;
                bqkv_s[j] = (j < 384) ? sbq[j] : (j < 768 ? sbk[j - 384] : sbv[j - 768]);
            } else {
                int k = i - 1920;  // 0..7
                int b = k / H_, h = k % H_;
                float s = gb[h];
                for (int n = 0; n < NM_; n++)
                    s += mc[b * NM_ + n] * gW[h * NM_ + n];
                gates[k] = 1.f / (1.f + __expf(-s));
            }
        }
        return;
    }
    const float* s; u16* d; int n;
    switch (seg) {
        case 0:  s = cWq; d = Wq_c;            n = 147456; break;
        case 1:  s = cWk; d = Wkv_c;           n = 147456; break;
        case 2:  s = cWv; d = Wkv_c + 147456;  n = 147456; break;
        case 3:  s = cWo; d = Wco;             n = 147456; break;
        case 4:  s = sWq; d = Wqkv_s;          n = 147456; break;
        case 5:  s = sWk; d = Wqkv_s + 147456; n = 147456; break;
        case 6:  s = sWv; d = Wqkv_s + 294912; n = 147456; break;
        case 7:  s = sWo; d = Wso;             n = 147456; break;
        case 8:  s = f1W; d = Wf1;             n = 589824; break;
        case 9:  s = f2W; d = Wf2;             n = 589824; break;
        case 10: s = adA; d = WadA;            n = 24576;  break;
        case 11: s = adB; d = WadB;            n = 24576;  break;
        default: s = mem; d = memb;            n = 1572864; break;
    }
    for (int i = blockIdx.x * 256 + threadIdx.x; i < n; i += gridDim.x * 256)
        d[i] = f2bf(s[i]);
}

// ---------------- LayerNorm: fp32 in, bf16 out ----------------
__global__ __launch_bounds__(384)
void ln_kernel(const float* __restrict__ x, const float* __restrict__ g,
               const float* __restrict__ b, u16* __restrict__ out) {
    __shared__ float sm[8];
    int row = blockIdx.x;
    int t = threadIdx.x;
    float v = x[(long)row * D_ + t];

    float s = v;
    for (int o = 32; o > 0; o >>= 1) s += __shfl_down(s, o);
    if ((t & 63) == 0) sm[t >> 6] = s;
    __syncthreads();
    float mu = 0.f;
    for (int i = 0; i < 6; i++) mu += sm[i];
    mu *= (1.f / D_);
    __syncthreads();

    float d = v - mu;
    s = d * d;
    for (int o = 32; o > 0; o >>= 1) s += __shfl_down(s, o);
    if ((t & 63) == 0) sm[t >> 6] = s;
    __syncthreads();
    float var = 0.f;
    for (int i = 0; i < 6; i++) var += sm[i];
    var *= (1.f / D_);

    float r = rsqrtf(var + 1e-5f);
    out[(long)row * D_ + t] = f2bf(d * r * g[t] + b[t]);
}

// ---------------- MFMA GEMM: C[NR,NC] = act(A[NR,K] @ W[NC,K]^T + bias) + res ----------------
// 64x64 block tile, BK=32, 4 waves each computing 32x32 (2x2 MFMA tiles of 16x16x32).
template<int ACT, bool OBF>
__global__ __launch_bounds__(256)
void gemm_mfma(const u16* __restrict__ A, const u16* __restrict__ W,
               const float* __restrict__ bias, const float* __restrict__ res,
               void* __restrict__ Cout, int NR, int NC, int K,
               const int* __restrict__ aidx, int astride) {
    if (aidx) W += (long)aidx[0] * astride;
    __shared__ __align__(16) u16 As[2048];   // 64x32 bf16, frag-ordered
    __shared__ __align__(16) u16 Ws[2048];
    int tid = threadIdx.x;
    int w = tid >> 6, lane = tid & 63;
    int bm = blockIdx.y * 64, bn = blockIdx.x * 64;
    int mt0 = (w & 1) * 2, nt0 = (w >> 1) * 2;

    int srow = ((tid >> 6) << 4) + (tid & 15);   // staging row 0..63
    int kq8  = ((tid >> 4) & 3) * 8;             // staging k-offset 0..24
    const u16* Ag = A + (long)(bm + srow) * K + kq8;
    int wrow = bn + srow;
    const u16* Wg = W + (long)wrow * K + kq8;
    bool wok = wrow < NC;

    f32x4 acc[2][2];
    #pragma unroll
    for (int i = 0; i < 2; i++)
        #pragma unroll
        for (int j = 0; j < 2; j++) acc[i][j] = (f32x4){0.f, 0.f, 0.f, 0.f};

    for (int k0 = 0; k0 < K; k0 += 32) {
        u16x8 av = {0, 0, 0, 0, 0, 0, 0, 0};
        u16x8 wv = {0, 0, 0, 0, 0, 0, 0, 0};
        bool kok = (k0 + kq8) < K;
        if (kok) av = *(const u16x8*)(Ag + k0);
        if (kok && wok) wv = *(const u16x8*)(Wg + k0);
        __syncthreads();
        *(u16x8*)(As + tid * 8) = av;
        *(u16x8*)(Ws + tid * 8) = wv;
        __syncthreads();
        u16x8 af[2], bfv[2];
        #pragma unroll
        for (int i = 0; i < 2; i++) {
            af[i]  = *(const u16x8*)(As + (mt0 + i) * 512 + lane * 8);
            bfv[i] = *(const u16x8*)(Ws + (nt0 + i) * 512 + lane * 8);
        }
        #pragma unroll
        for (int i = 0; i < 2; i++)
            #pragma unroll
            for (int j = 0; j < 2; j++)
                acc[i][j] = __builtin_amdgcn_mfma_f32_16x16x32_bf16(
                    as_bf(af[i]), as_bf(bfv[j]), acc[i][j], 0, 0, 0);
    }

    int quad = lane >> 4, l15 = lane & 15;
    #pragma unroll
    for (int mi = 0; mi < 2; mi++) {
        #pragma unroll
        for (int nj = 0; nj < 2; nj++) {
            int col = bn + (nt0 + nj) * 16 + l15;
            if (col < NC) {
                float bv = bias ? bias[col] : 0.f;
                int rowb = bm + (mt0 + mi) * 16 + quad * 4;
                #pragma unroll
                for (int r = 0; r < 4; r++) {
                    float v = acc[mi][nj][r] + bv;
                    if (ACT == 1) v = 0.5f * v * (1.f + erff(v * 0.70710678118654752f));
                    long idx = (long)(rowb + r) * NC + col;
                    if (res) v += res[idx];
                    if (OBF) ((u16*)Cout)[idx] = f2bf(v);
                    else     ((float*)Cout)[idx] = v;
                }
            }
        }
    }
}

// ---------------- V transpose: [B,2048 rows, istride] cols(384 slice) -> Vt [B][384][2048] ----------------
__global__ __launch_bounds__(256)
void transp_kernel(const u16* __restrict__ in, int istride, u16* __restrict__ out) {
    __shared__ __align__(16) u16 tile[64 * 72];
    int b = blockIdx.z;
    int r0 = blockIdx.x * 64;   // key rows
    int c0 = blockIdx.y * 64;   // V cols
    const u16* ib = in + (long)(b * 2048 + r0) * istride + c0;
    #pragma unroll
    for (int it = 0; it < 2; it++) {
        int c = threadIdx.x + it * 256;
        int i = c >> 3, jq = c & 7;
        *(u16x8*)&tile[i * 72 + jq * 8] = *(const u16x8*)(ib + (long)i * istride + jq * 8);
    }
    __syncthreads();
    u16* ob = out + (long)(b * 384 + c0) * 2048 + r0;
    #pragma unroll
    for (int it = 0; it < 2; it++) {
        int c = threadIdx.x + it * 256;
        int i2 = c >> 3, jq = c & 7;
        u16x8 v;
        #pragma unroll
        for (int e = 0; e < 8; e++) v[e] = tile[(jq * 8 + e) * 72 + i2];
        *(u16x8*)(ob + (long)i2 * 2048 + jq * 8) = v;
    }
}

// ---------------- Flash attention, bf16 MFMA, key-split x4 ----------------
// grid (32, 8, 4): 64 Q-rows per block (16/wave), one (b,h) per y, 512 keys per z-split.
// Writes unnormalized O partials (f32) + per-row m,l to workspace.
__global__ __launch_bounds__(256)
void attn_mfma(const u16* __restrict__ Qg, int qs,
               const u16* __restrict__ Kg, int ks,
               const u16* __restrict__ Vt,
               float* __restrict__ Po, float* __restrict__ Pm, float* __restrict__ Pl) {
    __shared__ __align__(16) u16 Ks[6144];        // 64 keys x 96 dh, frag-ordered
    __shared__ __align__(16) u16 Vs[96 * 72];     // V^T chunk: [dh][64 keys] padded to 72
    __shared__ __align__(16) u16 Ps[4 * 1088];    // per-wave P, A-frag-ordered
    const float SCALE = 0.10206207261596575f;     // 1/sqrt(96)

    int tid = threadIdx.x, wv = tid >> 6, lane = tid & 63;
    int l15 = lane & 15, quad = lane >> 4;
    int bh = blockIdx.y, b = bh >> 2, h = bh & 3;
    int split = blockIdx.z;
    int q0 = blockIdx.x * 64 + wv * 16;

    const u16* Qb = Qg + (long)(b * 2048 + q0) * qs + h * 96;
    const u16* Kb = Kg + (long)(b * 2048 + split * 512) * ks + h * 96;
    const u16* Vb = Vt + (long)(b * 384 + h * 96) * 2048 + split * 512;

    u16x8 qf[3];
    #pragma unroll
    for (int t = 0; t < 3; t++)
        qf[t] = *(const u16x8*)(Qb + (long)l15 * qs + t * 32 + quad * 8);

    f32x4 o[6];
    #pragma unroll
    for (int i = 0; i < 6; i++) o[i] = (f32x4){0.f, 0.f, 0.f, 0.f};
    float mi[4], li[4];
    #pragma unroll
    for (int r = 0; r < 4; r++) { mi[r] = -3e38f; li[r] = 0.f; }
    u16* Pw = Ps + wv * 1088;

    for (int j0 = 0; j0 < 512; j0 += 64) {
        // prefetch staging into regs
        u16x8 kst[3], vst[3];
        #pragma unroll
        for (int i = 0; i < 3; i++) {
            int c = tid + i * 256;
            int key = c & 63, dhg = c >> 6;
            kst[i] = *(const u16x8*)(Kb + (long)(j0 + key) * ks + dhg * 8);
            int dh = c >> 3, part = c & 7;
            vst[i] = *(const u16x8*)(Vb + (long)dh * 2048 + j0 + part * 8);
        }
        __syncthreads();
        #pragma unroll
        for (int i = 0; i < 3; i++) {
            int c = tid + i * 256;
            int key = c & 63, dhg = c >> 6;
            *(u16x8*)(Ks + (key >> 4) * 1536 + (dhg >> 2) * 512 + (dhg & 3) * 128 + (key & 15) * 8) = kst[i];
            int dh = c >> 3, part = c & 7;
            *(u16x8*)(Vs + dh * 72 + part * 8) = vst[i];
        }
        __syncthreads();

        // scores: 4 key-subtiles x 3 k-steps
        f32x4 sc[4];
        #pragma unroll
        for (int s = 0; s < 4; s++) sc[s] = (f32x4){0.f, 0.f, 0.f, 0.f};
        #pragma unroll
        for (int s = 0; s < 4; s++)
            #pragma unroll
            for (int t = 0; t < 3; t++) {
                u16x8 kf = *(const u16x8*)(Ks + s * 1536 + t * 512 + lane * 8);
                sc[s] = __builtin_amdgcn_mfma_f32_16x16x32_bf16(as_bf(qf[t]), as_bf(kf), sc[s], 0, 0, 0);
            }
        #pragma unroll
        for (int s = 0; s < 4; s++)
            #pragma unroll
            for (int r = 0; r < 4; r++) sc[s][r] *= SCALE;

        // online softmax: rows = quad*4+r, 16 lanes per quad hold 16 keys
        float mc[4];
        #pragma unroll
        for (int r = 0; r < 4; r++)
            mc[r] = fmaxf(fmaxf(sc[0][r], sc[1][r]), fmaxf(sc[2][r], sc[3][r]));
        #pragma unroll
        for (int off = 1; off < 16; off <<= 1)
            #pragma unroll
            for (int r = 0; r < 4; r++) mc[r] = fmaxf(mc[r], __shfl_xor(mc[r], off));
        float alpha[4], rs[4];
        #pragma unroll
        for (int r = 0; r < 4; r++) {
            float mn = fmaxf(mi[r], mc[r]);
            alpha[r] = __expf(mi[r] - mn);
            mi[r] = mn;
            rs[r] = 0.f;
        }
        #pragma unroll
        for (int s = 0; s < 4; s++)
            #pragma unroll
            for (int r = 0; r < 4; r++) {
                float p = __expf(sc[s][r] - mi[r]);
                sc[s][r] = p;
                rs[r] += p;
            }
        #pragma unroll
        for (int off = 1; off < 16; off <<= 1)
            #pragma unroll
            for (int r = 0; r < 4; r++) rs[r] += __shfl_xor(rs[r], off);
        #pragma unroll
        for (int r = 0; r < 4; r++) li[r] = li[r] * alpha[r] + rs[r];
        #pragma unroll
        for (int nt = 0; nt < 6; nt++)
            #pragma unroll
            for (int r = 0; r < 4; r++) o[nt][r] *= alpha[r];

        // write P (C-layout -> A-frag-ordered LDS), per-wave private
        #pragma unroll
        for (int s = 0; s < 4; s++) {
            int base = (s >> 1) * 544 + ((((s & 1) << 1) | (l15 >> 3))) * 136 + (l15 & 7);
            #pragma unroll
            for (int r = 0; r < 4; r++)
                Pw[base + (quad * 4 + r) * 8] = f2bf(sc[s][r]);
        }
        // PV: 2 k-steps (32 keys each) x 6 dh-tiles
        #pragma unroll
        for (int t2 = 0; t2 < 2; t2++) {
            u16x8 pf = *(const u16x8*)(Pw + t2 * 544 + quad * 136 + l15 * 8);
            #pragma unroll
            for (int nt = 0; nt < 6; nt++) {
                u16x8 vf = *(const u16x8*)(Vs + (nt * 16 + l15) * 72 + t2 * 32 + quad * 8);
                o[nt] = __builtin_amdgcn_mfma_f32_16x16x32_bf16(as_bf(pf), as_bf(vf), o[nt], 0, 0, 0);
            }
        }
    }

    // write unnormalized partials
    float* Pob = Po + ((long)(split * 8 + bh) * 2048 + q0) * 96;
    #pragma unroll
    for (int nt = 0; nt < 6; nt++)
        #pragma unroll
        for (int r = 0; r < 4; r++)
            Pob[(long)(quad * 4 + r) * 96 + nt * 16 + l15] = o[nt][r];
    if (l15 == 0) {
        long mb = (long)(split * 8 + bh) * 2048 + q0 + quad * 4;
        #pragma unroll
        for (int r = 0; r < 4; r++) { Pm[mb + r] = mi[r]; Pl[mb + r] = li[r]; }
    }
}

// ---------------- combine 4 key-split partials -> Z (bf16, gate/l applied) ----------------
// grid (32, 8): 64 rows per block, one bh per y. 256 threads: 64 rows x 4 dh-quarters.
__global__ __launch_bounds__(256)
void attn_combine(const float* __restrict__ Po, const float* __restrict__ Pm,
                  const float* __restrict__ Pl, const float* __restrict__ gates,
                  u16* __restrict__ Z) {
    int bh = blockIdx.y, b = bh >> 2, h = bh & 3;
    int tid = threadIdx.x;
    int rl = tid >> 2, part = tid & 3;
    int row = blockIdx.x * 64 + rl;
    long rbase = (long)bh * 2048 + row;   // split stride = 16384 rows

    float m[4], M = -3e38f;
    #pragma unroll
    for (int s = 0; s < 4; s++) { m[s] = Pm[s * 16384 + rbase]; M = fmaxf(M, m[s]); }
    float L = 0.f, w[4];
    #pragma unroll
    for (int s = 0; s < 4; s++) {
        float e = __expf(m[s] - M);
        w[s] = e;
        L += e * Pl[s * 16384 + rbase];
    }
    float g = gates ? gates[bh] : 1.f;
    float sc = g / L;
    #pragma unroll
    for (int s = 0; s < 4; s++) w[s] *= sc;

    u16* Zr = Z + ((long)(b * 2048) + row) * 384 + h * 96 + part * 24;
    #pragma unroll
    for (int i = 0; i < 24; i += 4) {
        f32x4 acc = (f32x4){0.f, 0.f, 0.f, 0.f};
        #pragma unroll
        for (int s = 0; s < 4; s++) {
            f32x4 v = *(const f32x4*)(Po + ((long)s * 16384 + rbase) * 96 + part * 24 + i);
            #pragma unroll
            for (int e = 0; e < 4; e++) acc[e] += w[s] * v[e];
        }
        u16x4 ov;
        #pragma unroll
        for (int e = 0; e < 4; e++) ov[e] = f2bf(acc[e]);
        *(u16x4*)(Zr + i) = ov;
    }
}

// ---------------- Launch ----------------
extern "C" void kernel_launch(void* const* d_in, const int* in_sizes, int n_in,
                              void* d_out, int out_size, void* d_ws, size_t ws_size,
                              hipStream_t stream) {
    const float* x    = (const float*)d_in[0];
    const float* mem  = (const float*)d_in[1];
    const float* mc   = (const float*)d_in[2];
    const int*   aidx = (const int*)d_in[3];
    const float* cWq = (const float*)d_in[4],  *cbq = (const float*)d_in[5];
    const float* cWk = (const float*)d_in[6],  *cbk = (const float*)d_in[7];
    const float* cWv = (const float*)d_in[8],  *cbv = (const float*)d_in[9];
    const float* cWo = (const float*)d_in[10], *cbo = (const float*)d_in[11];
    const float* sWq = (const float*)d_in[12], *sbq = (const float*)d_in[13];
    const float* sWk = (const float*)d_in[14], *sbk = (const float*)d_in[15];
    const float* sWv = (const float*)d_in[16], *sbv = (const float*)d_in[17];
    const float* sWo = (const float*)d_in[18], *sbo = (const float*)d_in[19];
    const float* gW  = (const float*)d_in[20], *gb  = (const float*)d_in[21];
    const float* f1W = (const float*)d_in[22], *f1b = (const float*)d_in[23];
    const float* f2W = (const float*)d_in[24], *f2b = (const float*)d_in[25];
    const float* adA = (const float*)d_in[26], *adB = (const float*)d_in[27];
    const float* ln1g = (const float*)d_in[28], *ln1b = (const float*)d_in[29];
    const float* ln2g = (const float*)d_in[30], *ln2b = (const float*)d_in[31];
    const float* ln3g = (const float*)d_in[32], *ln3b = (const float*)d_in[33];

    // ---- workspace layout ----
    u16* p = (u16*)d_ws;
    u16* H      = p; p += (size_t)NR_ * 384;
    u16* bufQ   = p; p += (size_t)NR_ * 384;
    u16* bufKV  = p; p += (size_t)NR_ * 768;
    u16* bufQKV = p; p += (size_t)NR_ * 1152;
    u16* Vt     = p; p += (size_t)B_ * 384 * 2048;
    u16* Zb     = p; p += (size_t)NR_ * 384;
    u16* F      = p; p += (size_t)NR_ * 1536;
    u16* Tl     = p; p += (size_t)NR_ * 16;
    u16* memb   = p; p += (size_t)NR_ * 384;
    u16* Wq_c   = p; p += 147456;
    u16* Wkv_c  = p; p += 294912;
    u16* Wco    = p; p += 147456;
    u16* Wqkv_s = p; p += 442368;
    u16* Wso    = p; p += 147456;
    u16* Wf1    = p; p += 589824;
    u16* Wf2    = p; p += 589824;
    u16* WadA   = p; p += 24576;
    u16* WadB   = p; p += 24576;
    float* fp = (float*)p;
    float* X1 = fp;     fp += (size_t)NR_ * 384;
    float* X2 = fp;     fp += (size_t)NR_ * 384;
    float* X3 = fp;     fp += (size_t)NR_ * 384;
    float* Po = fp;     fp += (size_t)4 * 8 * 2048 * 96;   // 6.29M floats
    float* Pm = fp;     fp += (size_t)4 * 8 * 2048;
    float* Pl = fp;     fp += (size_t)4 * 8 * 2048;
    float* bkv_c  = fp; fp += 768;
    float* bqkv_s = fp; fp += 1152;
    float* gbuf   = fp; fp += 8;

    // ---- fused setup ----
    setup_kernel<<<dim3(96, 14), 256, 0, stream>>>(
        cWq, cWk, cWv, cWo, sWq, sWk, sWv, sWo, f1W, f2W, adA, adB, mem,
        Wq_c, Wkv_c, Wco, Wqkv_s, Wso, Wf1, Wf2, WadA, WadB, memb,
        cbk, cbv, sbq, sbk, sbv, bkv_c, bqkv_s, mc, gW, gb, gbuf);

    const float* nf = nullptr;
    // --- cross-attention ---
    ln_kernel<<<NR_, 384, 0, stream>>>(x, ln1g, ln1b, H);
    gemm_mfma<0, true><<<dim3(6, 64), 256, 0, stream>>>(H, Wq_c, cbq, nf, bufQ, NR_, 384, 384, nullptr, 0);
    gemm_mfma<0, true><<<dim3(12, 64), 256, 0, stream>>>(memb, Wkv_c, bkv_c, nf, bufKV, NR_, 768, 384, nullptr, 0);
    transp_kernel<<<dim3(32, 6, 2), 256, 0, stream>>>(bufKV + 384, 768, Vt);
    attn_mfma<<<dim3(32, 8, 4), 256, 0, stream>>>(bufQ, 384, bufKV, 768, Vt, Po, Pm, Pl);
    attn_combine<<<dim3(32, 8), 256, 0, stream>>>(Po, Pm, Pl, nullptr, Zb);
    gemm_mfma<0, false><<<dim3(6, 64), 256, 0, stream>>>(Zb, Wco, cbo, x, X1, NR_, 384, 384, nullptr, 0);

    // --- motif-gated self-attention ---
    ln_kernel<<<NR_, 384, 0, stream>>>(X1, ln2g, ln2b, H);
    gemm_mfma<0, true><<<dim3(18, 64), 256, 0, stream>>>(H, Wqkv_s, bqkv_s, nf, bufQKV, NR_, 1152, 384, nullptr, 0);
    transp_kernel<<<dim3(32, 6, 2), 256, 0, stream>>>(bufQKV + 768, 1152, Vt);
    attn_mfma<<<dim3(32, 8, 4), 256, 0, stream>>>(bufQKV, 1152, bufQKV + 384, 1152, Vt, Po, Pm, Pl);
    attn_combine<<<dim3(32, 8), 256, 0, stream>>>(Po, Pm, Pl, gbuf, Zb);
    gemm_mfma<0, false><<<dim3(6, 64), 256, 0, stream>>>(Zb, Wso, sbo, X1, X2, NR_, 384, 384, nullptr, 0);

    // --- FFN + LoRA ---
    ln_kernel<<<NR_, 384, 0, stream>>>(X2, ln3g, ln3b, H);
    gemm_mfma<1, true><<<dim3(24, 64), 256, 0, stream>>>(H, Wf1, f1b, nf, F, NR_, 1536, 384, nullptr, 0);
    gemm_mfma<0, true><<<dim3(1, 64), 256, 0, stream>>>(H, WadA, nullptr, nf, Tl, NR_, 16, 384, aidx, R_ * D_);
    gemm_mfma<0, false><<<dim3(6, 64), 256, 0, stream>>>(F, Wf2, f2b, X2, X3, NR_, 384, 1536, nullptr, 0);
    gemm_mfma<0, false><<<dim3(6, 64), 256, 0, stream>>>(Tl, WadB, nullptr, X3, d_out, NR_, 384, 16, aidx, D_ * R_);
}

// Round 6
// 389.429 us; speedup vs baseline: 8.0850x; 1.0695x over previous
//
#include <hip/hip_runtime.h>
#include <hip/hip_bf16.h>
#include <math.h>

// Problem constants
#define B_   2
#define T_   2048
#define M_   2048
#define D_   384
#define H_   4
#define DH_  96
#define NM_  8
#define DF_  1536
#define R_   16
#define NR_  4096   // B*T = B*M rows

typedef unsigned short u16;
typedef u16    u16x8  __attribute__((ext_vector_type(8)));
typedef u16    u16x4  __attribute__((ext_vector_type(4)));
typedef __bf16 bf16x8 __attribute__((ext_vector_type(8)));
typedef float  f32x4  __attribute__((ext_vector_type(4)));

union V8 { u16x8 u; bf16x8 b; };
__device__ __forceinline__ bf16x8 as_bf(u16x8 x) { V8 v; v.u = x; return v.b; }

__device__ __forceinline__ u16 f2bf(float f) {
    unsigned u = __float_as_uint(f);
    unsigned r = (u + 0x7fffu + ((u >> 16) & 1u)) >> 16;
    return (u16)r;
}

// async global->LDS: 16B per lane, dest = wave-uniform base + lane*16
__device__ __forceinline__ void load16(const u16* g, u16* l) {
    __builtin_amdgcn_global_load_lds(
        (const __attribute__((address_space(1))) void*)g,
        (__attribute__((address_space(3))) void*)l, 16, 0, 0);
}

// ---------------- fused setup: weight converts + bias pack + gates ----------------
__global__ __launch_bounds__(256)
void setup_kernel(const float* cWq, const float* cWk, const float* cWv, const float* cWo,
                  const float* sWq, const float* sWk, const float* sWv, const float* sWo,
                  const float* f1W, const float* f2W, const float* adA, const float* adB,
                  const float* mem,
                  u16* Wq_c, u16* Wkv_c, u16* Wco, u16* Wqkv_s, u16* Wso,
                  u16* Wf1, u16* Wf2, u16* WadA, u16* WadB, u16* memb,
                  const float* cbk, const float* cbv,
                  const float* sbq, const float* sbk, const float* sbv,
                  float* bkv_c, float* bqkv_s,
                  const float* mc, const float* gW, const float* gb, float* gates) {
    int seg = blockIdx.y;
    if (seg == 13) {
        for (int i = blockIdx.x * 256 + threadIdx.x; i < 1928; i += gridDim.x * 256) {
            if (i < 768) bkv_c[i] = (i < 384) ? cbk[i] : cbv[i - 384];
            else if (i < 1920) {
                int j = i - 768;
                bqkv_s[j] = (j < 384) ? sbq[j] : (j < 768 ? sbk[j - 384] : sbv[j - 768]);
            } else {
                int k = i - 1920;  // 0..7
                int b = k / H_, h = k % H_;
                float s = gb[h];
                for (int n = 0; n < NM_; n++)
                    s += mc[b * NM_ + n] * gW[h * NM_ + n];
                gates[k] = 1.f / (1.f + __expf(-s));
            }
        }
        return;
    }
    const float* s; u16* d; int n;
    switch (seg) {
        case 0:  s = cWq; d = Wq_c;            n = 147456; break;
        case 1:  s = cWk; d = Wkv_c;           n = 147456; break;
        case 2:  s = cWv; d = Wkv_c + 147456;  n = 147456; break;
        case 3:  s = cWo; d = Wco;             n = 147456; break;
        case 4:  s = sWq; d = Wqkv_s;          n = 147456; break;
        case 5:  s = sWk; d = Wqkv_s + 147456; n = 147456; break;
        case 6:  s = sWv; d = Wqkv_s + 294912; n = 147456; break;
        case 7:  s = sWo; d = Wso;             n = 147456; break;
        case 8:  s = f1W; d = Wf1;             n = 589824; break;
        case 9:  s = f2W; d = Wf2;             n = 589824; break;
        case 10: s = adA; d = WadA;            n = 24576;  break;
        case 11: s = adB; d = WadB;            n = 24576;  break;
        default: s = mem; d = memb;            n = 1572864; break;
    }
    for (int i = blockIdx.x * 256 + threadIdx.x; i < n; i += gridDim.x * 256)
        d[i] = f2bf(s[i]);
}

// ---------------- LayerNorm: fp32 in, bf16 out ----------------
__global__ __launch_bounds__(384)
void ln_kernel(const float* __restrict__ x, const float* __restrict__ g,
               const float* __restrict__ b, u16* __restrict__ out) {
    __shared__ float sm[8];
    int row = blockIdx.x;
    int t = threadIdx.x;
    float v = x[(long)row * D_ + t];

    float s = v;
    for (int o = 32; o > 0; o >>= 1) s += __shfl_down(s, o);
    if ((t & 63) == 0) sm[t >> 6] = s;
    __syncthreads();
    float mu = 0.f;
    for (int i = 0; i < 6; i++) mu += sm[i];
    mu *= (1.f / D_);
    __syncthreads();

    float d = v - mu;
    s = d * d;
    for (int o = 32; o > 0; o >>= 1) s += __shfl_down(s, o);
    if ((t & 63) == 0) sm[t >> 6] = s;
    __syncthreads();
    float var = 0.f;
    for (int i = 0; i < 6; i++) var += sm[i];
    var *= (1.f / D_);

    float r = rsqrtf(var + 1e-5f);
    out[(long)row * D_ + t] = f2bf(d * r * g[t] + b[t]);
}

// ---------------- fast MFMA GEMM (NC%64==0, K%64==0): BK=64, global_load_lds ----------------
// 64x64 tile, 4 waves x (32x32), frag-ordered LDS regions of 512 u16 (one per (mtile,kc)).
template<int ACT, bool OBF>
__global__ __launch_bounds__(256)
void gemm64(const u16* __restrict__ A, const u16* __restrict__ W,
            const float* __restrict__ bias, const float* __restrict__ res,
            void* __restrict__ Cout, int NC, int K) {
    __shared__ __align__(16) u16 As[4096];
    __shared__ __align__(16) u16 Ws[4096];
    int tid = threadIdx.x, w = tid >> 6, lane = tid & 63;
    int l15 = lane & 15, quad = lane >> 4;
    int bm = blockIdx.y * 64, bn = blockIdx.x * 64;
    int mt0 = (w & 1) * 2, nt0 = (w >> 1) * 2;

    // staging descriptors: issue i covers region r=i*4+w, mtile=r>>1, kc=r&1
    const u16* Ag[2]; const u16* Wg[2]; u16* Al[2]; u16* Wl[2];
    #pragma unroll
    for (int i = 0; i < 2; i++) {
        int r = i * 4 + w, mt = r >> 1, kc = r & 1;
        Ag[i] = A + (long)(bm + mt * 16 + l15) * K + kc * 32 + quad * 8;
        Wg[i] = W + (long)(bn + mt * 16 + l15) * K + kc * 32 + quad * 8;
        Al[i] = As + r * 512;
        Wl[i] = Ws + r * 512;
    }

    f32x4 acc[2][2];
    #pragma unroll
    for (int i = 0; i < 2; i++)
        #pragma unroll
        for (int j = 0; j < 2; j++) acc[i][j] = (f32x4){0.f, 0.f, 0.f, 0.f};

    for (int k0 = 0; k0 < K; k0 += 64) {
        __syncthreads();
        #pragma unroll
        for (int i = 0; i < 2; i++) {
            load16(Ag[i] + k0, Al[i]);
            load16(Wg[i] + k0, Wl[i]);
        }
        __syncthreads();
        #pragma unroll
        for (int kc = 0; kc < 2; kc++) {
            u16x8 af[2], bfv[2];
            #pragma unroll
            for (int i = 0; i < 2; i++) {
                af[i]  = *(const u16x8*)(As + ((mt0 + i) * 2 + kc) * 512 + lane * 8);
                bfv[i] = *(const u16x8*)(Ws + ((nt0 + i) * 2 + kc) * 512 + lane * 8);
            }
            #pragma unroll
            for (int i = 0; i < 2; i++)
                #pragma unroll
                for (int j = 0; j < 2; j++)
                    acc[i][j] = __builtin_amdgcn_mfma_f32_16x16x32_bf16(
                        as_bf(af[i]), as_bf(bfv[j]), acc[i][j], 0, 0, 0);
        }
    }

    #pragma unroll
    for (int mi = 0; mi < 2; mi++) {
        #pragma unroll
        for (int nj = 0; nj < 2; nj++) {
            int col = bn + (nt0 + nj) * 16 + l15;
            float bv = bias ? bias[col] : 0.f;
            int rowb = bm + (mt0 + mi) * 16 + quad * 4;
            #pragma unroll
            for (int r = 0; r < 4; r++) {
                float v = acc[mi][nj][r] + bv;
                if (ACT == 1) v = 0.5f * v * (1.f + erff(v * 0.70710678118654752f));
                long idx = (long)(rowb + r) * NC + col;
                if (res) v += res[idx];
                if (OBF) ((u16*)Cout)[idx] = f2bf(v);
                else     ((float*)Cout)[idx] = v;
            }
        }
    }
}

// ---------------- small guarded GEMM (LoRA): register staging, BK=32 ----------------
template<int ACT, bool OBF>
__global__ __launch_bounds__(256)
void gemm_small(const u16* __restrict__ A, const u16* __restrict__ W,
                const float* __restrict__ bias, const float* __restrict__ res,
                void* __restrict__ Cout, int NR, int NC, int K,
                const int* __restrict__ aidx, int astride) {
    if (aidx) W += (long)aidx[0] * astride;
    __shared__ __align__(16) u16 As[2048];
    __shared__ __align__(16) u16 Ws[2048];
    int tid = threadIdx.x;
    int w = tid >> 6, lane = tid & 63;
    int bm = blockIdx.y * 64, bn = blockIdx.x * 64;
    int mt0 = (w & 1) * 2, nt0 = (w >> 1) * 2;

    int srow = ((tid >> 6) << 4) + (tid & 15);
    int kq8  = ((tid >> 4) & 3) * 8;
    const u16* Ag = A + (long)(bm + srow) * K + kq8;
    int wrow = bn + srow;
    const u16* Wg = W + (long)wrow * K + kq8;
    bool wok = wrow < NC;

    f32x4 acc[2][2];
    #pragma unroll
    for (int i = 0; i < 2; i++)
        #pragma unroll
        for (int j = 0; j < 2; j++) acc[i][j] = (f32x4){0.f, 0.f, 0.f, 0.f};

    for (int k0 = 0; k0 < K; k0 += 32) {
        u16x8 av = {0, 0, 0, 0, 0, 0, 0, 0};
        u16x8 wv = {0, 0, 0, 0, 0, 0, 0, 0};
        bool kok = (k0 + kq8) < K;
        if (kok) av = *(const u16x8*)(Ag + k0);
        if (kok && wok) wv = *(const u16x8*)(Wg + k0);
        __syncthreads();
        *(u16x8*)(As + tid * 8) = av;
        *(u16x8*)(Ws + tid * 8) = wv;
        __syncthreads();
        u16x8 af[2], bfv[2];
        #pragma unroll
        for (int i = 0; i < 2; i++) {
            af[i]  = *(const u16x8*)(As + (mt0 + i) * 512 + lane * 8);
            bfv[i] = *(const u16x8*)(Ws + (nt0 + i) * 512 + lane * 8);
        }
        #pragma unroll
        for (int i = 0; i < 2; i++)
            #pragma unroll
            for (int j = 0; j < 2; j++)
                acc[i][j] = __builtin_amdgcn_mfma_f32_16x16x32_bf16(
                    as_bf(af[i]), as_bf(bfv[j]), acc[i][j], 0, 0, 0);
    }

    int quad = lane >> 4, l15 = lane & 15;
    #pragma unroll
    for (int mi = 0; mi < 2; mi++) {
        #pragma unroll
        for (int nj = 0; nj < 2; nj++) {
            int col = bn + (nt0 + nj) * 16 + l15;
            if (col < NC) {
                float bv = bias ? bias[col] : 0.f;
                int rowb = bm + (mt0 + mi) * 16 + quad * 4;
                #pragma unroll
                for (int r = 0; r < 4; r++) {
                    float v = acc[mi][nj][r] + bv;
                    if (ACT == 1) v = 0.5f * v * (1.f + erff(v * 0.70710678118654752f));
                    long idx = (long)(rowb + r) * NC + col;
                    if (res) v += res[idx];
                    if (OBF) ((u16*)Cout)[idx] = f2bf(v);
                    else     ((float*)Cout)[idx] = v;
                }
            }
        }
    }
}

// ---------------- V transpose: [B,2048 rows, istride] cols(384 slice) -> Vt [B][384][2048] ----------------
__global__ __launch_bounds__(256)
void transp_kernel(const u16* __restrict__ in, int istride, u16* __restrict__ out) {
    __shared__ __align__(16) u16 tile[64 * 72];
    int b = blockIdx.z;
    int r0 = blockIdx.x * 64;
    int c0 = blockIdx.y * 64;
    const u16* ib = in + (long)(b * 2048 + r0) * istride + c0;
    #pragma unroll
    for (int it = 0; it < 2; it++) {
        int c = threadIdx.x + it * 256;
        int i = c >> 3, jq = c & 7;
        *(u16x8*)&tile[i * 72 + jq * 8] = *(const u16x8*)(ib + (long)i * istride + jq * 8);
    }
    __syncthreads();
    u16* ob = out + (long)(b * 384 + c0) * 2048 + r0;
    #pragma unroll
    for (int it = 0; it < 2; it++) {
        int c = threadIdx.x + it * 256;
        int i2 = c >> 3, jq = c & 7;
        u16x8 v;
        #pragma unroll
        for (int e = 0; e < 8; e++) v[e] = tile[(jq * 8 + e) * 72 + i2];
        *(u16x8*)(ob + (long)i2 * 2048 + jq * 8) = v;
    }
}

// ---------------- Flash attention, bf16 MFMA, key-split x4, no-max softmax ----------------
// grid (32, 8, 4). Scores are tiny (sigma~0.15): exp without max-subtraction is exact.
__global__ __launch_bounds__(256)
void attn_mfma(const u16* __restrict__ Qg, int qs,
               const u16* __restrict__ Kg, int ks,
               const u16* __restrict__ Vt,
               float* __restrict__ Po, float* __restrict__ Pl) {
    __shared__ __align__(16) u16 Ks[6144];   // 12 regions of 512: region = ksub*3+kstep
    __shared__ __align__(16) u16 Vs[6144];   // 12 regions of 512: region = nt*2+t2
    __shared__ __align__(16) u16 Ps[4 * 1088];
    const float SCALE = 0.10206207261596575f;  // 1/sqrt(96)

    int tid = threadIdx.x, wv = tid >> 6, lane = tid & 63;
    int l15 = lane & 15, quad = lane >> 4;
    int bh = blockIdx.y, b = bh >> 2, h = bh & 3;
    int split = blockIdx.z;
    int q0 = blockIdx.x * 64 + wv * 16;

    const u16* Qb = Qg + (long)(b * 2048 + q0) * qs + h * 96;
    const u16* Kb = Kg + (long)(b * 2048 + split * 512) * ks + h * 96;
    const u16* Vb = Vt + (long)(b * 384 + h * 96) * 2048 + split * 512;

    u16x8 qf[3];
    #pragma unroll
    for (int t = 0; t < 3; t++)
        qf[t] = *(const u16x8*)(Qb + (long)l15 * qs + t * 32 + quad * 8);

    f32x4 o[6];
    #pragma unroll
    for (int i = 0; i < 6; i++) o[i] = (f32x4){0.f, 0.f, 0.f, 0.f};
    float rs[4] = {0.f, 0.f, 0.f, 0.f};
    u16* Pw = Ps + wv * 1088;

    // per-issue staging descriptors (uniform per wave)
    const u16* KgI[3]; u16* KlI[3]; const u16* VgI[3]; u16* VlI[3];
    #pragma unroll
    for (int i = 0; i < 3; i++) {
        int r = i * 4 + wv;
        int ksub = r & 3, kst = r >> 2;
        KgI[i] = Kb + (long)(ksub * 16 + l15) * ks + kst * 32 + quad * 8;
        KlI[i] = Ks + (ksub * 3 + kst) * 512;
        int nt = r >> 1, t2 = r & 1;
        VgI[i] = Vb + (long)(nt * 16 + l15) * 2048 + t2 * 32 + quad * 8;
        VlI[i] = Vs + r * 512;
    }

    for (int j0 = 0; j0 < 512; j0 += 64) {
        __syncthreads();
        #pragma unroll
        for (int i = 0; i < 3; i++) {
            load16(KgI[i] + (long)j0 * ks, KlI[i]);
            load16(VgI[i] + j0, VlI[i]);
        }
        __syncthreads();

        // scores: 4 key-subtiles x 3 k-steps
        f32x4 sc[4];
        #pragma unroll
        for (int s = 0; s < 4; s++) sc[s] = (f32x4){0.f, 0.f, 0.f, 0.f};
        #pragma unroll
        for (int s = 0; s < 4; s++)
            #pragma unroll
            for (int t = 0; t < 3; t++) {
                u16x8 kf = *(const u16x8*)(Ks + (s * 3 + t) * 512 + lane * 8);
                sc[s] = __builtin_amdgcn_mfma_f32_16x16x32_bf16(as_bf(qf[t]), as_bf(kf), sc[s], 0, 0, 0);
            }

        // p = exp(s*scale); accumulate per-lane sums; write P to LDS (A-frag order)
        #pragma unroll
        for (int s = 0; s < 4; s++) {
            int base = (s >> 1) * 544 + ((((s & 1) << 1) | (l15 >> 3))) * 136 + (l15 & 7);
            #pragma unroll
            for (int r = 0; r < 4; r++) {
                float p = __expf(sc[s][r] * SCALE);
                rs[r] += p;
                Pw[base + (quad * 4 + r) * 8] = f2bf(p);
            }
        }
        // PV: 2 k-steps (32 keys each) x 6 dh-tiles
        #pragma unroll
        for (int t2 = 0; t2 < 2; t2++) {
            u16x8 pf = *(const u16x8*)(Pw + t2 * 544 + quad * 136 + l15 * 8);
            #pragma unroll
            for (int nt = 0; nt < 6; nt++) {
                u16x8 vf = *(const u16x8*)(Vs + (nt * 2 + t2) * 512 + lane * 8);
                o[nt] = __builtin_amdgcn_mfma_f32_16x16x32_bf16(as_bf(pf), as_bf(vf), o[nt], 0, 0, 0);
            }
        }
    }

    // single final 16-lane sum reduce (per quad group)
    #pragma unroll
    for (int off = 1; off < 16; off <<= 1)
        #pragma unroll
        for (int r = 0; r < 4; r++) rs[r] += __shfl_xor(rs[r], off);

    float* Pob = Po + ((long)(split * 8 + bh) * 2048 + q0) * 96;
    #pragma unroll
    for (int nt = 0; nt < 6; nt++)
        #pragma unroll
        for (int r = 0; r < 4; r++)
            Pob[(long)(quad * 4 + r) * 96 + nt * 16 + l15] = o[nt][r];
    if (l15 == 0) {
        long mb = (long)(split * 8 + bh) * 2048 + q0 + quad * 4;
        #pragma unroll
        for (int r = 0; r < 4; r++) Pl[mb + r] = rs[r];
    }
}

// ---------------- combine 4 key-split partials -> Z (bf16, gate/l applied) ----------------
__global__ __launch_bounds__(256)
void attn_combine(const float* __restrict__ Po, const float* __restrict__ Pl,
                  const float* __restrict__ gates, u16* __restrict__ Z) {
    int bh = blockIdx.y, b = bh >> 2, h = bh & 3;
    int tid = threadIdx.x;
    int rl = tid >> 2, part = tid & 3;
    int row = blockIdx.x * 64 + rl;
    long rbase = (long)bh * 2048 + row;

    float L = 0.f;
    #pragma unroll
    for (int s = 0; s < 4; s++) L += Pl[s * 16384 + rbase];
    float g = gates ? gates[bh] : 1.f;
    float sc = g / L;

    u16* Zr = Z + ((long)(b * 2048) + row) * 384 + h * 96 + part * 24;
    #pragma unroll
    for (int i = 0; i < 24; i += 4) {
        f32x4 acc = (f32x4){0.f, 0.f, 0.f, 0.f};
        #pragma unroll
        for (int s = 0; s < 4; s++) {
            f32x4 v = *(const f32x4*)(Po + ((long)s * 16384 + rbase) * 96 + part * 24 + i);
            #pragma unroll
            for (int e = 0; e < 4; e++) acc[e] += v[e];
        }
        u16x4 ov;
        #pragma unroll
        for (int e = 0; e < 4; e++) ov[e] = f2bf(acc[e] * sc);
        *(u16x4*)(Zr + i) = ov;
    }
}

// ---------------- Launch ----------------
extern "C" void kernel_launch(void* const* d_in, const int* in_sizes, int n_in,
                              void* d_out, int out_size, void* d_ws, size_t ws_size,
                              hipStream_t stream) {
    const float* x    = (const float*)d_in[0];
    const float* mem  = (const float*)d_in[1];
    const float* mc   = (const float*)d_in[2];
    const int*   aidx = (const int*)d_in[3];
    const float* cWq = (const float*)d_in[4],  *cbq = (const float*)d_in[5];
    const float* cWk = (const float*)d_in[6],  *cbk = (const float*)d_in[7];
    const float* cWv = (const float*)d_in[8],  *cbv = (const float*)d_in[9];
    const float* cWo = (const float*)d_in[10], *cbo = (const float*)d_in[11];
    const float* sWq = (const float*)d_in[12], *sbq = (const float*)d_in[13];
    const float* sWk = (const float*)d_in[14], *sbk = (const float*)d_in[15];
    const float* sWv = (const float*)d_in[16], *sbv = (const float*)d_in[17];
    const float* sWo = (const float*)d_in[18], *sbo = (const float*)d_in[19];
    const float* gW  = (const float*)d_in[20], *gb  = (const float*)d_in[21];
    const float* f1W = (const float*)d_in[22], *f1b = (const float*)d_in[23];
    const float* f2W = (const float*)d_in[24], *f2b = (const float*)d_in[25];
    const float* adA = (const float*)d_in[26], *adB = (const float*)d_in[27];
    const float* ln1g = (const float*)d_in[28], *ln1b = (const float*)d_in[29];
    const float* ln2g = (const float*)d_in[30], *ln2b = (const float*)d_in[31];
    const float* ln3g = (const float*)d_in[32], *ln3b = (const float*)d_in[33];

    // ---- workspace layout ----
    u16* p = (u16*)d_ws;
    u16* H      = p; p += (size_t)NR_ * 384;
    u16* bufQ   = p; p += (size_t)NR_ * 384;
    u16* bufKV  = p; p += (size_t)NR_ * 768;
    u16* bufQKV = p; p += (size_t)NR_ * 1152;
    u16* Vt     = p; p += (size_t)B_ * 384 * 2048;
    u16* Zb     = p; p += (size_t)NR_ * 384;
    u16* F      = p; p += (size_t)NR_ * 1536;
    u16* Tl     = p; p += (size_t)NR_ * 16;
    u16* memb   = p; p += (size_t)NR_ * 384;
    u16* Wq_c   = p; p += 147456;
    u16* Wkv_c  = p; p += 294912;
    u16* Wco    = p; p += 147456;
    u16* Wqkv_s = p; p += 442368;
    u16* Wso    = p; p += 147456;
    u16* Wf1    = p; p += 589824;
    u16* Wf2    = p; p += 589824;
    u16* WadA   = p; p += 24576;
    u16* WadB   = p; p += 24576;
    float* fp = (float*)p;
    float* X1 = fp;     fp += (size_t)NR_ * 384;
    float* X2 = fp;     fp += (size_t)NR_ * 384;
    float* X3 = fp;     fp += (size_t)NR_ * 384;
    float* Po = fp;     fp += (size_t)4 * 8 * 2048 * 96;
    float* Pl = fp;     fp += (size_t)4 * 8 * 2048;
    float* bkv_c  = fp; fp += 768;
    float* bqkv_s = fp; fp += 1152;
    float* gbuf   = fp; fp += 8;

    // ---- fused setup ----
    setup_kernel<<<dim3(96, 14), 256, 0, stream>>>(
        cWq, cWk, cWv, cWo, sWq, sWk, sWv, sWo, f1W, f2W, adA, adB, mem,
        Wq_c, Wkv_c, Wco, Wqkv_s, Wso, Wf1, Wf2, WadA, WadB, memb,
        cbk, cbv, sbq, sbk, sbv, bkv_c, bqkv_s, mc, gW, gb, gbuf);

    const float* nf = nullptr;
    // --- cross-attention ---
    ln_kernel<<<NR_, 384, 0, stream>>>(x, ln1g, ln1b, H);
    gemm64<0, true><<<dim3(6, 64), 256, 0, stream>>>(H, Wq_c, cbq, nf, bufQ, 384, 384);
    gemm64<0, true><<<dim3(12, 64), 256, 0, stream>>>(memb, Wkv_c, bkv_c, nf, bufKV, 768, 384);
    transp_kernel<<<dim3(32, 6, 2), 256, 0, stream>>>(bufKV + 384, 768, Vt);
    attn_mfma<<<dim3(32, 8, 4), 256, 0, stream>>>(bufQ, 384, bufKV, 768, Vt, Po, Pl);
    attn_combine<<<dim3(32, 8), 256, 0, stream>>>(Po, Pl, nullptr, Zb);
    gemm64<0, false><<<dim3(6, 64), 256, 0, stream>>>(Zb, Wco, cbo, x, X1, 384, 384);

    // --- motif-gated self-attention ---
    ln_kernel<<<NR_, 384, 0, stream>>>(X1, ln2g, ln2b, H);
    gemm64<0, true><<<dim3(18, 64), 256, 0, stream>>>(H, Wqkv_s, bqkv_s, nf, bufQKV, 1152, 384);
    transp_kernel<<<dim3(32, 6, 2), 256, 0, stream>>>(bufQKV + 768, 1152, Vt);
    attn_mfma<<<dim3(32, 8, 4), 256, 0, stream>>>(bufQKV, 1152, bufQKV + 384, 1152, Vt, Po, Pl);
    attn_combine<<<dim3(32, 8), 256, 0, stream>>>(Po, Pl, gbuf, Zb);
    gemm64<0, false><<<dim3(6, 64), 256, 0, stream>>>(Zb, Wso, sbo, X1, X2, 384, 384);

    // --- FFN + LoRA ---
    ln_kernel<<<NR_, 384, 0, stream>>>(X2, ln3g, ln3b, H);
    gemm64<1, true><<<dim3(24, 64), 256, 0, stream>>>(H, Wf1, f1b, nf, F, 1536, 384);
    gemm_small<0, true><<<dim3(1, 64), 256, 0, stream>>>(H, WadA, nullptr, nf, Tl, NR_, 16, 384, aidx, R_ * D_);
    gemm64<0, false><<<dim3(6, 64), 256, 0, stream>>>(F, Wf2, f2b, X2, X3, 384, 1536);
    gemm_small<0, false><<<dim3(6, 64), 256, 0, stream>>>(Tl, WadB, nullptr, X3, d_out, NR_, 384, 16, aidx, D_ * R_);
}

// Round 7
// 380.691 us; speedup vs baseline: 8.2706x; 1.0230x over previous
//
#include <hip/hip_runtime.h>
#include <hip/hip_bf16.h>
#include <math.h>

// Problem constants
#define B_   2
#define T_   2048
#define M_   2048
#define D_   384
#define H_   4
#define DH_  96
#define NM_  8
#define DF_  1536
#define R_   16
#define NR_  4096   // B*T = B*M rows

typedef unsigned short u16;
typedef u16    u16x8  __attribute__((ext_vector_type(8)));
typedef u16    u16x4  __attribute__((ext_vector_type(4)));
typedef __bf16 bf16x8 __attribute__((ext_vector_type(8)));
typedef float  f32x4  __attribute__((ext_vector_type(4)));

union V8 { u16x8 u; bf16x8 b; };
__device__ __forceinline__ bf16x8 as_bf(u16x8 x) { V8 v; v.u = x; return v.b; }

__device__ __forceinline__ u16 f2bf(float f) {
    unsigned u = __float_as_uint(f);
    unsigned r = (u + 0x7fffu + ((u >> 16) & 1u)) >> 16;
    return (u16)r;
}

// async global->LDS: 16B per lane, dest = wave-uniform base + lane*16
__device__ __forceinline__ void load16(const u16* g, u16* l) {
    __builtin_amdgcn_global_load_lds(
        (const __attribute__((address_space(1))) void*)g,
        (__attribute__((address_space(3))) void*)l, 16, 0, 0);
}

// ---------------- fused setup: weight converts + bias pack + gates ----------------
__global__ __launch_bounds__(256)
void setup_kernel(const float* cWq, const float* cWk, const float* cWv, const float* cWo,
                  const float* sWq, const float* sWk, const float* sWv, const float* sWo,
                  const float* f1W, const float* f2W, const float* adA, const float* adB,
                  const float* mem,
                  u16* Wq_c, u16* Wkv_c, u16* Wco, u16* Wqkv_s, u16* Wso,
                  u16* Wf1, u16* Wf2, u16* WadA, u16* WadB, u16* memb,
                  const float* cbk, const float* cbv,
                  const float* sbq, const float* sbk, const float* sbv,
                  float* bkv_c, float* bqkv_s,
                  const float* mc, const float* gW, const float* gb, float* gates) {
    int seg = blockIdx.y;
    if (seg == 13) {
        for (int i = blockIdx.x * 256 + threadIdx.x; i < 1928; i += gridDim.x * 256) {
            if (i < 768) bkv_c[i] = (i < 384) ? cbk[i] : cbv[i - 384];
            else if (i < 1920) {
                int j = i - 768;
                bqkv_s[j] = (j < 384) ? sbq[j] : (j < 768 ? sbk[j - 384] : sbv[j - 768]);
            } else {
                int k = i - 1920;  // 0..7
                int b = k / H_, h = k % H_;
                float s = gb[h];
                for (int n = 0; n < NM_; n++)
                    s += mc[b * NM_ + n] * gW[h * NM_ + n];
                gates[k] = 1.f / (1.f + __expf(-s));
            }
        }
        return;
    }
    const float* s; u16* d; int n;
    switch (seg) {
        case 0:  s = cWq; d = Wq_c;            n = 147456; break;
        case 1:  s = cWk; d = Wkv_c;           n = 147456; break;
        case 2:  s = cWv; d = Wkv_c + 147456;  n = 147456; break;
        case 3:  s = cWo; d = Wco;             n = 147456; break;
        case 4:  s = sWq; d = Wqkv_s;          n = 147456; break;
        case 5:  s = sWk; d = Wqkv_s + 147456; n = 147456; break;
        case 6:  s = sWv; d = Wqkv_s + 294912; n = 147456; break;
        case 7:  s = sWo; d = Wso;             n = 147456; break;
        case 8:  s = f1W; d = Wf1;             n = 589824; break;
        case 9:  s = f2W; d = Wf2;             n = 589824; break;
        case 10: s = adA; d = WadA;            n = 24576;  break;
        case 11: s = adB; d = WadB;            n = 24576;  break;
        default: s = mem; d = memb;            n = 1572864; break;
    }
    for (int i = blockIdx.x * 256 + threadIdx.x; i < n; i += gridDim.x * 256)
        d[i] = f2bf(s[i]);
}

// ---------------- LayerNorm: fp32 in, bf16 out ----------------
__global__ __launch_bounds__(384)
void ln_kernel(const float* __restrict__ x, const float* __restrict__ g,
               const float* __restrict__ b, u16* __restrict__ out) {
    __shared__ float sm[8];
    int row = blockIdx.x;
    int t = threadIdx.x;
    float v = x[(long)row * D_ + t];

    float s = v;
    for (int o = 32; o > 0; o >>= 1) s += __shfl_down(s, o);
    if ((t & 63) == 0) sm[t >> 6] = s;
    __syncthreads();
    float mu = 0.f;
    for (int i = 0; i < 6; i++) mu += sm[i];
    mu *= (1.f / D_);
    __syncthreads();

    float d = v - mu;
    s = d * d;
    for (int o = 32; o > 0; o >>= 1) s += __shfl_down(s, o);
    if ((t & 63) == 0) sm[t >> 6] = s;
    __syncthreads();
    float var = 0.f;
    for (int i = 0; i < 6; i++) var += sm[i];
    var *= (1.f / D_);

    float r = rsqrtf(var + 1e-5f);
    out[(long)row * D_ + t] = f2bf(d * r * g[t] + b[t]);
}

// ---------------- pipelined MFMA GEMM (NC%64==0, K%64==0) ----------------
// 64x64 tile, BK=64, double-buffered LDS, ONE barrier per K-iter, DMA prefetch
// issued before the MFMA of the current iter so it flies during compute.
// VT: cols >= vtbase are written transposed into Vt[B][384][2048] instead.
// LORA: adds (Tl @ adB[aidx]^T) to acc via one extra MFMA per tile pair.
template<int ACT, bool OBF, bool VT, bool LORA>
__global__ __launch_bounds__(256)
void gemm_pipe(const u16* __restrict__ A, const u16* __restrict__ W,
               const float* __restrict__ bias, const float* __restrict__ res,
               void* __restrict__ Cout, int NC, int K,
               u16* __restrict__ Vt, int vtbase,
               const u16* __restrict__ Tl, const u16* __restrict__ adB,
               const int* __restrict__ aidx) {
    __shared__ __align__(16) u16 As[8192];   // 2 buffers x 4096
    __shared__ __align__(16) u16 Ws[8192];
    int tid = threadIdx.x, w = tid >> 6, lane = tid & 63;
    int l15 = lane & 15, quad = lane >> 4;
    int bm = blockIdx.y * 64, bn = blockIdx.x * 64;
    int mt0 = (w & 1) * 2, nt0 = (w >> 1) * 2;

    // staging descriptors: issue s covers region r=s*4+w, mtile=r>>1, kc=r&1
    const u16* Ag[2]; const u16* Wg[2]; u16* Al[2]; u16* Wl[2];
    #pragma unroll
    for (int s = 0; s < 2; s++) {
        int r = s * 4 + w, mt = r >> 1, kc = r & 1;
        Ag[s] = A + (long)(bm + mt * 16 + l15) * K + kc * 32 + quad * 8;
        Wg[s] = W + (long)(bn + mt * 16 + l15) * K + kc * 32 + quad * 8;
        Al[s] = As + r * 512;
        Wl[s] = Ws + r * 512;
    }

    f32x4 acc[2][2];
    #pragma unroll
    for (int i = 0; i < 2; i++)
        #pragma unroll
        for (int j = 0; j < 2; j++) acc[i][j] = (f32x4){0.f, 0.f, 0.f, 0.f};

    int niter = K >> 6;
    // prologue: prefetch iter 0 into buffer 0
    #pragma unroll
    for (int s = 0; s < 2; s++) { load16(Ag[s], Al[s]); load16(Wg[s], Wl[s]); }

    for (int i = 0; i < niter; i++) {
        __syncthreads();   // drains DMA of buf[i&1]; protects buf[(i+1)&1] from overwrite
        int cur = (i & 1) * 4096, nxt = 4096 - cur;
        if (i + 1 < niter) {
            int k = (i + 1) << 6;
            #pragma unroll
            for (int s = 0; s < 2; s++) {
                load16(Ag[s] + k, Al[s] + nxt);
                load16(Wg[s] + k, Wl[s] + nxt);
            }
        }
        #pragma unroll
        for (int kc = 0; kc < 2; kc++) {
            u16x8 af[2], bfv[2];
            #pragma unroll
            for (int s = 0; s < 2; s++) {
                af[s]  = *(const u16x8*)(As + cur + ((mt0 + s) * 2 + kc) * 512 + lane * 8);
                bfv[s] = *(const u16x8*)(Ws + cur + ((nt0 + s) * 2 + kc) * 512 + lane * 8);
            }
            #pragma unroll
            for (int s = 0; s < 2; s++)
                #pragma unroll
                for (int j = 0; j < 2; j++)
                    acc[s][j] = __builtin_amdgcn_mfma_f32_16x16x32_bf16(
                        as_bf(af[s]), as_bf(bfv[j]), acc[s][j], 0, 0, 0);
        }
    }

    if (LORA) {
        long aoff = (long)aidx[0] * 6144;   // 384*16
        u16x8 tlf[2] = {{0,0,0,0,0,0,0,0}, {0,0,0,0,0,0,0,0}};
        u16x8 adf[2] = {{0,0,0,0,0,0,0,0}, {0,0,0,0,0,0,0,0}};
        #pragma unroll
        for (int s = 0; s < 2; s++) {
            if (quad < 2) {
                tlf[s] = *(const u16x8*)(Tl + (long)(bm + (mt0 + s) * 16 + l15) * 16 + quad * 8);
                adf[s] = *(const u16x8*)(adB + aoff + (long)(bn + (nt0 + s) * 16 + l15) * 16 + quad * 8);
            }
        }
        #pragma unroll
        for (int s = 0; s < 2; s++)
            #pragma unroll
            for (int j = 0; j < 2; j++)
                acc[s][j] = __builtin_amdgcn_mfma_f32_16x16x32_bf16(
                    as_bf(tlf[s]), as_bf(adf[j]), acc[s][j], 0, 0, 0);
    }

    #pragma unroll
    for (int mi = 0; mi < 2; mi++) {
        #pragma unroll
        for (int nj = 0; nj < 2; nj++) {
            int col = bn + (nt0 + nj) * 16 + l15;
            float bv = bias ? bias[col] : 0.f;
            int rowb = bm + (mt0 + mi) * 16 + quad * 4;
            if (VT && col >= vtbase) {
                // transposed V write: Vt[b][vc][row], 4 consecutive rows per lane
                int vc = col - vtbase;
                int b = rowb >> 11, rowl = rowb & 2047;
                u16x4 ov;
                #pragma unroll
                for (int r = 0; r < 4; r++) ov[r] = f2bf(acc[mi][nj][r] + bv);
                *(u16x4*)(Vt + ((long)b * 384 + vc) * 2048 + rowl) = ov;
            } else {
                #pragma unroll
                for (int r = 0; r < 4; r++) {
                    float v = acc[mi][nj][r] + bv;
                    if (ACT == 1) v = 0.5f * v * (1.f + erff(v * 0.70710678118654752f));
                    long idx = (long)(rowb + r) * NC + col;
                    if (res) v += res[idx];
                    if (OBF) ((u16*)Cout)[idx] = f2bf(v);
                    else     ((float*)Cout)[idx] = v;
                }
            }
        }
    }
}

// ---------------- small guarded GEMM (LoRA-A): register staging, BK=32 ----------------
template<int ACT, bool OBF>
__global__ __launch_bounds__(256)
void gemm_small(const u16* __restrict__ A, const u16* __restrict__ W,
                const float* __restrict__ bias, const float* __restrict__ res,
                void* __restrict__ Cout, int NR, int NC, int K,
                const int* __restrict__ aidx, int astride) {
    if (aidx) W += (long)aidx[0] * astride;
    __shared__ __align__(16) u16 As[2048];
    __shared__ __align__(16) u16 Ws[2048];
    int tid = threadIdx.x;
    int w = tid >> 6, lane = tid & 63;
    int bm = blockIdx.y * 64, bn = blockIdx.x * 64;
    int mt0 = (w & 1) * 2, nt0 = (w >> 1) * 2;

    int srow = ((tid >> 6) << 4) + (tid & 15);
    int kq8  = ((tid >> 4) & 3) * 8;
    const u16* Ag = A + (long)(bm + srow) * K + kq8;
    int wrow = bn + srow;
    const u16* Wg = W + (long)wrow * K + kq8;
    bool wok = wrow < NC;

    f32x4 acc[2][2];
    #pragma unroll
    for (int i = 0; i < 2; i++)
        #pragma unroll
        for (int j = 0; j < 2; j++) acc[i][j] = (f32x4){0.f, 0.f, 0.f, 0.f};

    for (int k0 = 0; k0 < K; k0 += 32) {
        u16x8 av = {0, 0, 0, 0, 0, 0, 0, 0};
        u16x8 wv = {0, 0, 0, 0, 0, 0, 0, 0};
        bool kok = (k0 + kq8) < K;
        if (kok) av = *(const u16x8*)(Ag + k0);
        if (kok && wok) wv = *(const u16x8*)(Wg + k0);
        __syncthreads();
        *(u16x8*)(As + tid * 8) = av;
        *(u16x8*)(Ws + tid * 8) = wv;
        __syncthreads();
        u16x8 af[2], bfv[2];
        #pragma unroll
        for (int i = 0; i < 2; i++) {
            af[i]  = *(const u16x8*)(As + (mt0 + i) * 512 + lane * 8);
            bfv[i] = *(const u16x8*)(Ws + (nt0 + i) * 512 + lane * 8);
        }
        #pragma unroll
        for (int i = 0; i < 2; i++)
            #pragma unroll
            for (int j = 0; j < 2; j++)
                acc[i][j] = __builtin_amdgcn_mfma_f32_16x16x32_bf16(
                    as_bf(af[i]), as_bf(bfv[j]), acc[i][j], 0, 0, 0);
    }

    int quad = lane >> 4, l15 = lane & 15;
    #pragma unroll
    for (int mi = 0; mi < 2; mi++) {
        #pragma unroll
        for (int nj = 0; nj < 2; nj++) {
            int col = bn + (nt0 + nj) * 16 + l15;
            if (col < NC) {
                float bv = bias ? bias[col] : 0.f;
                int rowb = bm + (mt0 + mi) * 16 + quad * 4;
                #pragma unroll
                for (int r = 0; r < 4; r++) {
                    float v = acc[mi][nj][r] + bv;
                    if (ACT == 1) v = 0.5f * v * (1.f + erff(v * 0.70710678118654752f));
                    long idx = (long)(rowb + r) * NC + col;
                    if (res) v += res[idx];
                    if (OBF) ((u16*)Cout)[idx] = f2bf(v);
                    else     ((float*)Cout)[idx] = v;
                }
            }
        }
    }
}

// ---------------- Flash attention, bf16 MFMA, key-split x4, no-max softmax ----------------
__global__ __launch_bounds__(256)
void attn_mfma(const u16* __restrict__ Qg, int qs,
               const u16* __restrict__ Kg, int ks,
               const u16* __restrict__ Vt,
               float* __restrict__ Po, float* __restrict__ Pl) {
    __shared__ __align__(16) u16 Ks[6144];   // 12 regions of 512: region = ksub*3+kstep
    __shared__ __align__(16) u16 Vs[6144];   // 12 regions of 512: region = nt*2+t2
    __shared__ __align__(16) u16 Ps[4 * 1088];
    const float SCALE = 0.10206207261596575f;  // 1/sqrt(96)

    int tid = threadIdx.x, wv = tid >> 6, lane = tid & 63;
    int l15 = lane & 15, quad = lane >> 4;
    int bh = blockIdx.y, b = bh >> 2, h = bh & 3;
    int split = blockIdx.z;
    int q0 = blockIdx.x * 64 + wv * 16;

    const u16* Qb = Qg + (long)(b * 2048 + q0) * qs + h * 96;
    const u16* Kb = Kg + (long)(b * 2048 + split * 512) * ks + h * 96;
    const u16* Vb = Vt + (long)(b * 384 + h * 96) * 2048 + split * 512;

    u16x8 qf[3];
    #pragma unroll
    for (int t = 0; t < 3; t++)
        qf[t] = *(const u16x8*)(Qb + (long)l15 * qs + t * 32 + quad * 8);

    f32x4 o[6];
    #pragma unroll
    for (int i = 0; i < 6; i++) o[i] = (f32x4){0.f, 0.f, 0.f, 0.f};
    float rs[4] = {0.f, 0.f, 0.f, 0.f};
    u16* Pw = Ps + wv * 1088;

    const u16* KgI[3]; u16* KlI[3]; const u16* VgI[3]; u16* VlI[3];
    #pragma unroll
    for (int i = 0; i < 3; i++) {
        int r = i * 4 + wv;
        int ksub = r & 3, kst = r >> 2;
        KgI[i] = Kb + (long)(ksub * 16 + l15) * ks + kst * 32 + quad * 8;
        KlI[i] = Ks + (ksub * 3 + kst) * 512;
        int nt = r >> 1, t2 = r & 1;
        VgI[i] = Vb + (long)(nt * 16 + l15) * 2048 + t2 * 32 + quad * 8;
        VlI[i] = Vs + r * 512;
    }

    for (int j0 = 0; j0 < 512; j0 += 64) {
        __syncthreads();
        #pragma unroll
        for (int i = 0; i < 3; i++) {
            load16(KgI[i] + (long)j0 * ks, KlI[i]);
            load16(VgI[i] + j0, VlI[i]);
        }
        __syncthreads();

        f32x4 sc[4];
        #pragma unroll
        for (int s = 0; s < 4; s++) sc[s] = (f32x4){0.f, 0.f, 0.f, 0.f};
        #pragma unroll
        for (int s = 0; s < 4; s++)
            #pragma unroll
            for (int t = 0; t < 3; t++) {
                u16x8 kf = *(const u16x8*)(Ks + (s * 3 + t) * 512 + lane * 8);
                sc[s] = __builtin_amdgcn_mfma_f32_16x16x32_bf16(as_bf(qf[t]), as_bf(kf), sc[s], 0, 0, 0);
            }

        #pragma unroll
        for (int s = 0; s < 4; s++) {
            int base = (s >> 1) * 544 + ((((s & 1) << 1) | (l15 >> 3))) * 136 + (l15 & 7);
            #pragma unroll
            for (int r = 0; r < 4; r++) {
                float p = __expf(sc[s][r] * SCALE);
                rs[r] += p;
                Pw[base + (quad * 4 + r) * 8] = f2bf(p);
            }
        }
        #pragma unroll
        for (int t2 = 0; t2 < 2; t2++) {
            u16x8 pf = *(const u16x8*)(Pw + t2 * 544 + quad * 136 + l15 * 8);
            #pragma unroll
            for (int nt = 0; nt < 6; nt++) {
                u16x8 vf = *(const u16x8*)(Vs + (nt * 2 + t2) * 512 + lane * 8);
                o[nt] = __builtin_amdgcn_mfma_f32_16x16x32_bf16(as_bf(pf), as_bf(vf), o[nt], 0, 0, 0);
            }
        }
    }

    #pragma unroll
    for (int off = 1; off < 16; off <<= 1)
        #pragma unroll
        for (int r = 0; r < 4; r++) rs[r] += __shfl_xor(rs[r], off);

    float* Pob = Po + ((long)(split * 8 + bh) * 2048 + q0) * 96;
    #pragma unroll
    for (int nt = 0; nt < 6; nt++)
        #pragma unroll
        for (int r = 0; r < 4; r++)
            Pob[(long)(quad * 4 + r) * 96 + nt * 16 + l15] = o[nt][r];
    if (l15 == 0) {
        long mb = (long)(split * 8 + bh) * 2048 + q0 + quad * 4;
        #pragma unroll
        for (int r = 0; r < 4; r++) Pl[mb + r] = rs[r];
    }
}

// ---------------- combine 4 key-split partials -> Z (bf16, gate/l applied) ----------------
__global__ __launch_bounds__(256)
void attn_combine(const float* __restrict__ Po, const float* __restrict__ Pl,
                  const float* __restrict__ gates, u16* __restrict__ Z) {
    int bh = blockIdx.y, b = bh >> 2, h = bh & 3;
    int tid = threadIdx.x;
    int rl = tid >> 2, part = tid & 3;
    int row = blockIdx.x * 64 + rl;
    long rbase = (long)bh * 2048 + row;

    float L = 0.f;
    #pragma unroll
    for (int s = 0; s < 4; s++) L += Pl[s * 16384 + rbase];
    float g = gates ? gates[bh] : 1.f;
    float sc = g / L;

    u16* Zr = Z + ((long)(b * 2048) + row) * 384 + h * 96 + part * 24;
    #pragma unroll
    for (int i = 0; i < 24; i += 4) {
        f32x4 acc = (f32x4){0.f, 0.f, 0.f, 0.f};
        #pragma unroll
        for (int s = 0; s < 4; s++) {
            f32x4 v = *(const f32x4*)(Po + ((long)s * 16384 + rbase) * 96 + part * 24 + i);
            #pragma unroll
            for (int e = 0; e < 4; e++) acc[e] += v[e];
        }
        u16x4 ov;
        #pragma unroll
        for (int e = 0; e < 4; e++) ov[e] = f2bf(acc[e] * sc);
        *(u16x4*)(Zr + i) = ov;
    }
}

// ---------------- Launch ----------------
extern "C" void kernel_launch(void* const* d_in, const int* in_sizes, int n_in,
                              void* d_out, int out_size, void* d_ws, size_t ws_size,
                              hipStream_t stream) {
    const float* x    = (const float*)d_in[0];
    const float* mem  = (const float*)d_in[1];
    const float* mc   = (const float*)d_in[2];
    const int*   aidx = (const int*)d_in[3];
    const float* cWq = (const float*)d_in[4],  *cbq = (const float*)d_in[5];
    const float* cWk = (const float*)d_in[6],  *cbk = (const float*)d_in[7];
    const float* cWv = (const float*)d_in[8],  *cbv = (const float*)d_in[9];
    const float* cWo = (const float*)d_in[10], *cbo = (const float*)d_in[11];
    const float* sWq = (const float*)d_in[12], *sbq = (const float*)d_in[13];
    const float* sWk = (const float*)d_in[14], *sbk = (const float*)d_in[15];
    const float* sWv = (const float*)d_in[16], *sbv = (const float*)d_in[17];
    const float* sWo = (const float*)d_in[18], *sbo = (const float*)d_in[19];
    const float* gW  = (const float*)d_in[20], *gb  = (const float*)d_in[21];
    const float* f1W = (const float*)d_in[22], *f1b = (const float*)d_in[23];
    const float* f2W = (const float*)d_in[24], *f2b = (const float*)d_in[25];
    const float* adA = (const float*)d_in[26], *adB = (const float*)d_in[27];
    const float* ln1g = (const float*)d_in[28], *ln1b = (const float*)d_in[29];
    const float* ln2g = (const float*)d_in[30], *ln2b = (const float*)d_in[31];
    const float* ln3g = (const float*)d_in[32], *ln3b = (const float*)d_in[33];

    // ---- workspace layout ----
    u16* p = (u16*)d_ws;
    u16* H      = p; p += (size_t)NR_ * 384;
    u16* bufQ   = p; p += (size_t)NR_ * 384;
    u16* bufKV  = p; p += (size_t)NR_ * 768;
    u16* bufQKV = p; p += (size_t)NR_ * 1152;
    u16* Vt     = p; p += (size_t)B_ * 384 * 2048;
    u16* Zb     = p; p += (size_t)NR_ * 384;
    u16* F      = p; p += (size_t)NR_ * 1536;
    u16* Tl     = p; p += (size_t)NR_ * 16;
    u16* memb   = p; p += (size_t)NR_ * 384;
    u16* Wq_c   = p; p += 147456;
    u16* Wkv_c  = p; p += 294912;
    u16* Wco    = p; p += 147456;
    u16* Wqkv_s = p; p += 442368;
    u16* Wso    = p; p += 147456;
    u16* Wf1    = p; p += 589824;
    u16* Wf2    = p; p += 589824;
    u16* WadA   = p; p += 24576;
    u16* WadB   = p; p += 24576;
    float* fp = (float*)p;
    float* X1 = fp;     fp += (size_t)NR_ * 384;
    float* X2 = fp;     fp += (size_t)NR_ * 384;
    float* Po = fp;     fp += (size_t)4 * 8 * 2048 * 96;
    float* Pl = fp;     fp += (size_t)4 * 8 * 2048;
    float* bkv_c  = fp; fp += 768;
    float* bqkv_s = fp; fp += 1152;
    float* gbuf   = fp; fp += 8;

    // ---- fused setup ----
    setup_kernel<<<dim3(96, 14), 256, 0, stream>>>(
        cWq, cWk, cWv, cWo, sWq, sWk, sWv, sWo, f1W, f2W, adA, adB, mem,
        Wq_c, Wkv_c, Wco, Wqkv_s, Wso, Wf1, Wf2, WadA, WadB, memb,
        cbk, cbv, sbq, sbk, sbv, bkv_c, bqkv_s, mc, gW, gb, gbuf);

    const float* nf = nullptr;
    const u16* nu = nullptr;
    // --- cross-attention ---
    ln_kernel<<<NR_, 384, 0, stream>>>(x, ln1g, ln1b, H);
    gemm_pipe<0, true, false, false><<<dim3(6, 64), 256, 0, stream>>>(H, Wq_c, cbq, nf, bufQ, 384, 384, nullptr, 0, nu, nu, nullptr);
    gemm_pipe<0, true, true, false><<<dim3(12, 64), 256, 0, stream>>>(memb, Wkv_c, bkv_c, nf, bufKV, 768, 384, Vt, 384, nu, nu, nullptr);
    attn_mfma<<<dim3(32, 8, 4), 256, 0, stream>>>(bufQ, 384, bufKV, 768, Vt, Po, Pl);
    attn_combine<<<dim3(32, 8), 256, 0, stream>>>(Po, Pl, nullptr, Zb);
    gemm_pipe<0, false, false, false><<<dim3(6, 64), 256, 0, stream>>>(Zb, Wco, cbo, x, X1, 384, 384, nullptr, 0, nu, nu, nullptr);

    // --- motif-gated self-attention ---
    ln_kernel<<<NR_, 384, 0, stream>>>(X1, ln2g, ln2b, H);
    gemm_pipe<0, true, true, false><<<dim3(18, 64), 256, 0, stream>>>(H, Wqkv_s, bqkv_s, nf, bufQKV, 1152, 384, Vt, 768, nu, nu, nullptr);
    attn_mfma<<<dim3(32, 8, 4), 256, 0, stream>>>(bufQKV, 1152, bufQKV + 384, 1152, Vt, Po, Pl);
    attn_combine<<<dim3(32, 8), 256, 0, stream>>>(Po, Pl, gbuf, Zb);
    gemm_pipe<0, false, false, false><<<dim3(6, 64), 256, 0, stream>>>(Zb, Wso, sbo, X1, X2, 384, 384, nullptr, 0, nu, nu, nullptr);

    // --- FFN + LoRA (LoRA-B fused into f2 epilogue) ---
    ln_kernel<<<NR_, 384, 0, stream>>>(X2, ln3g, ln3b, H);
    gemm_pipe<1, true, false, false><<<dim3(24, 64), 256, 0, stream>>>(H, Wf1, f1b, nf, F, 1536, 384, nullptr, 0, nu, nu, nullptr);
    gemm_small<0, true><<<dim3(1, 64), 256, 0, stream>>>(H, WadA, nullptr, nf, Tl, NR_, 16, 384, aidx, R_ * D_);
    gemm_pipe<0, false, false, true><<<dim3(6, 64), 256, 0, stream>>>(F, Wf2, f2b, X2, d_out, 384, 1536, nullptr, 0, Tl, WadB, aidx);
}

// Round 8
// 371.616 us; speedup vs baseline: 8.4726x; 1.0244x over previous
//
#include <hip/hip_runtime.h>
#include <hip/hip_bf16.h>
#include <math.h>

// Problem constants
#define B_   2
#define T_   2048
#define M_   2048
#define D_   384
#define H_   4
#define DH_  96
#define NM_  8
#define DF_  1536
#define R_   16
#define NR_  4096   // B*T = B*M rows

typedef unsigned short u16;
typedef u16    u16x8  __attribute__((ext_vector_type(8)));
typedef u16    u16x4  __attribute__((ext_vector_type(4)));
typedef __bf16 bf16x8 __attribute__((ext_vector_type(8)));
typedef float  f32x4  __attribute__((ext_vector_type(4)));

union V8 { u16x8 u; bf16x8 b; };
__device__ __forceinline__ bf16x8 as_bf(u16x8 x) { V8 v; v.u = x; return v.b; }

__device__ __forceinline__ u16 f2bf(float f) {
    unsigned u = __float_as_uint(f);
    unsigned r = (u + 0x7fffu + ((u >> 16) & 1u)) >> 16;
    return (u16)r;
}

// async global->LDS: 16B per lane, dest = wave-uniform base + lane*16
__device__ __forceinline__ void load16(const u16* g, u16* l) {
    __builtin_amdgcn_global_load_lds(
        (const __attribute__((address_space(1))) void*)g,
        (__attribute__((address_space(3))) void*)l, 16, 0, 0);
}

// ---------------- fused setup: weight converts + bias pack + gates ----------------
__global__ __launch_bounds__(256)
void setup_kernel(const float* cWq, const float* cWk, const float* cWv, const float* cWo,
                  const float* sWq, const float* sWk, const float* sWv, const float* sWo,
                  const float* f1W, const float* f2W, const float* adA, const float* adB,
                  const float* mem,
                  u16* Wq_c, u16* Wkv_c, u16* Wco, u16* Wqkv_s, u16* Wso,
                  u16* Wf1, u16* Wf2, u16* WadA, u16* WadB, u16* memb,
                  const float* cbk, const float* cbv,
                  const float* sbq, const float* sbk, const float* sbv,
                  float* bkv_c, float* bqkv_s,
                  const float* mc, const float* gW, const float* gb, float* gates) {
    int seg = blockIdx.y;
    if (seg == 13) {
        for (int i = blockIdx.x * 256 + threadIdx.x; i < 1928; i += gridDim.x * 256) {
            if (i < 768) bkv_c[i] = (i < 384) ? cbk[i] : cbv[i - 384];
            else if (i < 1920) {
                int j = i - 768;
                bqkv_s[j] = (j < 384) ? sbq[j] : (j < 768 ? sbk[j - 384] : sbv[j - 768]);
            } else {
                int k = i - 1920;  // 0..7
                int b = k / H_, h = k % H_;
                float s = gb[h];
                for (int n = 0; n < NM_; n++)
                    s += mc[b * NM_ + n] * gW[h * NM_ + n];
                gates[k] = 1.f / (1.f + __expf(-s));
            }
        }
        return;
    }
    const float* s; u16* d; int n;
    switch (seg) {
        case 0:  s = cWq; d = Wq_c;            n = 147456; break;
        case 1:  s = cWk; d = Wkv_c;           n = 147456; break;
        case 2:  s = cWv; d = Wkv_c + 147456;  n = 147456; break;
        case 3:  s = cWo; d = Wco;             n = 147456; break;
        case 4:  s = sWq; d = Wqkv_s;          n = 147456; break;
        case 5:  s = sWk; d = Wqkv_s + 147456; n = 147456; break;
        case 6:  s = sWv; d = Wqkv_s + 294912; n = 147456; break;
        case 7:  s = sWo; d = Wso;             n = 147456; break;
        case 8:  s = f1W; d = Wf1;             n = 589824; break;
        case 9:  s = f2W; d = Wf2;             n = 589824; break;
        case 10: s = adA; d = WadA;            n = 24576;  break;
        case 11: s = adB; d = WadB;            n = 24576;  break;
        default: s = mem; d = memb;            n = 1572864; break;
    }
    for (int i = blockIdx.x * 256 + threadIdx.x; i < n; i += gridDim.x * 256)
        d[i] = f2bf(s[i]);
}

// ---------------- LayerNorm: fp32 in, bf16 out ----------------
__global__ __launch_bounds__(384)
void ln_kernel(const float* __restrict__ x, const float* __restrict__ g,
               const float* __restrict__ b, u16* __restrict__ out) {
    __shared__ float sm[8];
    int row = blockIdx.x;
    int t = threadIdx.x;
    float v = x[(long)row * D_ + t];

    float s = v;
    for (int o = 32; o > 0; o >>= 1) s += __shfl_down(s, o);
    if ((t & 63) == 0) sm[t >> 6] = s;
    __syncthreads();
    float mu = 0.f;
    for (int i = 0; i < 6; i++) mu += sm[i];
    mu *= (1.f / D_);
    __syncthreads();

    float d = v - mu;
    s = d * d;
    for (int o = 32; o > 0; o >>= 1) s += __shfl_down(s, o);
    if ((t & 63) == 0) sm[t >> 6] = s;
    __syncthreads();
    float var = 0.f;
    for (int i = 0; i < 6; i++) var += sm[i];
    var *= (1.f / D_);

    float r = rsqrtf(var + 1e-5f);
    out[(long)row * D_ + t] = f2bf(d * r * g[t] + b[t]);
}

// ---------------- pipelined MFMA GEMM (NC%64==0, K%64==0) ----------------
template<int ACT, bool OBF, bool VT, bool LORA>
__global__ __launch_bounds__(256)
void gemm_pipe(const u16* __restrict__ A, const u16* __restrict__ W,
               const float* __restrict__ bias, const float* __restrict__ res,
               void* __restrict__ Cout, int NC, int K,
               u16* __restrict__ Vt, int vtbase,
               const u16* __restrict__ Tl, const u16* __restrict__ adB,
               const int* __restrict__ aidx) {
    __shared__ __align__(16) u16 As[8192];   // 2 buffers x 4096
    __shared__ __align__(16) u16 Ws[8192];
    int tid = threadIdx.x, w = tid >> 6, lane = tid & 63;
    int l15 = lane & 15, quad = lane >> 4;
    int bm = blockIdx.y * 64, bn = blockIdx.x * 64;
    int mt0 = (w & 1) * 2, nt0 = (w >> 1) * 2;

    const u16* Ag[2]; const u16* Wg[2]; u16* Al[2]; u16* Wl[2];
    #pragma unroll
    for (int s = 0; s < 2; s++) {
        int r = s * 4 + w, mt = r >> 1, kc = r & 1;
        Ag[s] = A + (long)(bm + mt * 16 + l15) * K + kc * 32 + quad * 8;
        Wg[s] = W + (long)(bn + mt * 16 + l15) * K + kc * 32 + quad * 8;
        Al[s] = As + r * 512;
        Wl[s] = Ws + r * 512;
    }

    f32x4 acc[2][2];
    #pragma unroll
    for (int i = 0; i < 2; i++)
        #pragma unroll
        for (int j = 0; j < 2; j++) acc[i][j] = (f32x4){0.f, 0.f, 0.f, 0.f};

    int niter = K >> 6;
    #pragma unroll
    for (int s = 0; s < 2; s++) { load16(Ag[s], Al[s]); load16(Wg[s], Wl[s]); }

    for (int i = 0; i < niter; i++) {
        __syncthreads();
        int cur = (i & 1) * 4096, nxt = 4096 - cur;
        if (i + 1 < niter) {
            int k = (i + 1) << 6;
            #pragma unroll
            for (int s = 0; s < 2; s++) {
                load16(Ag[s] + k, Al[s] + nxt);
                load16(Wg[s] + k, Wl[s] + nxt);
            }
        }
        #pragma unroll
        for (int kc = 0; kc < 2; kc++) {
            u16x8 af[2], bfv[2];
            #pragma unroll
            for (int s = 0; s < 2; s++) {
                af[s]  = *(const u16x8*)(As + cur + ((mt0 + s) * 2 + kc) * 512 + lane * 8);
                bfv[s] = *(const u16x8*)(Ws + cur + ((nt0 + s) * 2 + kc) * 512 + lane * 8);
            }
            #pragma unroll
            for (int s = 0; s < 2; s++)
                #pragma unroll
                for (int j = 0; j < 2; j++)
                    acc[s][j] = __builtin_amdgcn_mfma_f32_16x16x32_bf16(
                        as_bf(af[s]), as_bf(bfv[j]), acc[s][j], 0, 0, 0);
        }
    }

    if (LORA) {
        long aoff = (long)aidx[0] * 6144;   // 384*16
        u16x8 tlf[2] = {{0,0,0,0,0,0,0,0}, {0,0,0,0,0,0,0,0}};
        u16x8 adf[2] = {{0,0,0,0,0,0,0,0}, {0,0,0,0,0,0,0,0}};
        #pragma unroll
        for (int s = 0; s < 2; s++) {
            if (quad < 2) {
                tlf[s] = *(const u16x8*)(Tl + (long)(bm + (mt0 + s) * 16 + l15) * 16 + quad * 8);
                adf[s] = *(const u16x8*)(adB + aoff + (long)(bn + (nt0 + s) * 16 + l15) * 16 + quad * 8);
            }
        }
        #pragma unroll
        for (int s = 0; s < 2; s++)
            #pragma unroll
            for (int j = 0; j < 2; j++)
                acc[s][j] = __builtin_amdgcn_mfma_f32_16x16x32_bf16(
                    as_bf(tlf[s]), as_bf(adf[j]), acc[s][j], 0, 0, 0);
    }

    #pragma unroll
    for (int mi = 0; mi < 2; mi++) {
        #pragma unroll
        for (int nj = 0; nj < 2; nj++) {
            int col = bn + (nt0 + nj) * 16 + l15;
            float bv = bias ? bias[col] : 0.f;
            int rowb = bm + (mt0 + mi) * 16 + quad * 4;
            if (VT && col >= vtbase) {
                int vc = col - vtbase;
                int b = rowb >> 11, rowl = rowb & 2047;
                u16x4 ov;
                #pragma unroll
                for (int r = 0; r < 4; r++) ov[r] = f2bf(acc[mi][nj][r] + bv);
                *(u16x4*)(Vt + ((long)b * 384 + vc) * 2048 + rowl) = ov;
            } else {
                #pragma unroll
                for (int r = 0; r < 4; r++) {
                    float v = acc[mi][nj][r] + bv;
                    if (ACT == 1) v = 0.5f * v * (1.f + erff(v * 0.70710678118654752f));
                    long idx = (long)(rowb + r) * NC + col;
                    if (res) v += res[idx];
                    if (OBF) ((u16*)Cout)[idx] = f2bf(v);
                    else     ((float*)Cout)[idx] = v;
                }
            }
        }
    }
}

// ---------------- small guarded GEMM (LoRA-A): register staging, BK=32 ----------------
template<int ACT, bool OBF>
__global__ __launch_bounds__(256)
void gemm_small(const u16* __restrict__ A, const u16* __restrict__ W,
                const float* __restrict__ bias, const float* __restrict__ res,
                void* __restrict__ Cout, int NR, int NC, int K,
                const int* __restrict__ aidx, int astride) {
    if (aidx) W += (long)aidx[0] * astride;
    __shared__ __align__(16) u16 As[2048];
    __shared__ __align__(16) u16 Ws[2048];
    int tid = threadIdx.x;
    int w = tid >> 6, lane = tid & 63;
    int bm = blockIdx.y * 64, bn = blockIdx.x * 64;
    int mt0 = (w & 1) * 2, nt0 = (w >> 1) * 2;

    int srow = ((tid >> 6) << 4) + (tid & 15);
    int kq8  = ((tid >> 4) & 3) * 8;
    const u16* Ag = A + (long)(bm + srow) * K + kq8;
    int wrow = bn + srow;
    const u16* Wg = W + (long)wrow * K + kq8;
    bool wok = wrow < NC;

    f32x4 acc[2][2];
    #pragma unroll
    for (int i = 0; i < 2; i++)
        #pragma unroll
        for (int j = 0; j < 2; j++) acc[i][j] = (f32x4){0.f, 0.f, 0.f, 0.f};

    for (int k0 = 0; k0 < K; k0 += 32) {
        u16x8 av = {0, 0, 0, 0, 0, 0, 0, 0};
        u16x8 wv = {0, 0, 0, 0, 0, 0, 0, 0};
        bool kok = (k0 + kq8) < K;
        if (kok) av = *(const u16x8*)(Ag + k0);
        if (kok && wok) wv = *(const u16x8*)(Wg + k0);
        __syncthreads();
        *(u16x8*)(As + tid * 8) = av;
        *(u16x8*)(Ws + tid * 8) = wv;
        __syncthreads();
        u16x8 af[2], bfv[2];
        #pragma unroll
        for (int i = 0; i < 2; i++) {
            af[i]  = *(const u16x8*)(As + (mt0 + i) * 512 + lane * 8);
            bfv[i] = *(const u16x8*)(Ws + (nt0 + i) * 512 + lane * 8);
        }
        #pragma unroll
        for (int i = 0; i < 2; i++)
            #pragma unroll
            for (int j = 0; j < 2; j++)
                acc[i][j] = __builtin_amdgcn_mfma_f32_16x16x32_bf16(
                    as_bf(af[i]), as_bf(bfv[j]), acc[i][j], 0, 0, 0);
    }

    int quad = lane >> 4, l15 = lane & 15;
    #pragma unroll
    for (int mi = 0; mi < 2; mi++) {
        #pragma unroll
        for (int nj = 0; nj < 2; nj++) {
            int col = bn + (nt0 + nj) * 16 + l15;
            if (col < NC) {
                float bv = bias ? bias[col] : 0.f;
                int rowb = bm + (mt0 + mi) * 16 + quad * 4;
                #pragma unroll
                for (int r = 0; r < 4; r++) {
                    float v = acc[mi][nj][r] + bv;
                    if (ACT == 1) v = 0.5f * v * (1.f + erff(v * 0.70710678118654752f));
                    long idx = (long)(rowb + r) * NC + col;
                    if (res) v += res[idx];
                    if (OBF) ((u16*)Cout)[idx] = f2bf(v);
                    else     ((float*)Cout)[idx] = v;
                }
            }
        }
    }
}

// ---------------- Flash attention: 32 Q-rows/wave (2 subtiles), dbuf K/V, key-split x4 ----------------
// grid (16, 8, 4): 128 Q-rows per block, one (b,h) per y, 512 keys per z-split.
// Every K/V LDS frag read feeds TWO MFMAs (one per Q-subtile) -> LDS traffic halved.
__global__ __launch_bounds__(256)
void attn_mfma(const u16* __restrict__ Qg, int qs,
               const u16* __restrict__ Kg, int ks,
               const u16* __restrict__ Vt,
               float* __restrict__ Po, float* __restrict__ Pl) {
    __shared__ __align__(16) u16 Ks[2][6144];   // dbuf; 12 regions of 512: region = ksub*3+kstep
    __shared__ __align__(16) u16 Vs[2][6144];   // dbuf; 12 regions of 512: region = nt*2+t2
    __shared__ __align__(16) u16 Ps[4][2][1088];
    const float SCALE = 0.10206207261596575f;  // 1/sqrt(96)

    int tid = threadIdx.x, wv = tid >> 6, lane = tid & 63;
    int l15 = lane & 15, quad = lane >> 4;
    int bh = blockIdx.y, b = bh >> 2, h = bh & 3;
    int split = blockIdx.z;
    int q0 = blockIdx.x * 128 + wv * 32;

    const u16* Qb = Qg + (long)(b * 2048 + q0) * qs + h * 96;
    const u16* Kb = Kg + (long)(b * 2048 + split * 512) * ks + h * 96;
    const u16* Vb = Vt + (long)(b * 384 + h * 96) * 2048 + split * 512;

    u16x8 qf[2][3];
    #pragma unroll
    for (int g = 0; g < 2; g++)
        #pragma unroll
        for (int t = 0; t < 3; t++)
            qf[g][t] = *(const u16x8*)(Qb + (long)(g * 16 + l15) * qs + t * 32 + quad * 8);

    f32x4 o[2][6];
    #pragma unroll
    for (int g = 0; g < 2; g++)
        #pragma unroll
        for (int i = 0; i < 6; i++) o[g][i] = (f32x4){0.f, 0.f, 0.f, 0.f};
    float rs[2][4] = {{0.f, 0.f, 0.f, 0.f}, {0.f, 0.f, 0.f, 0.f}};

    const u16* KgI[3]; int KlO[3]; const u16* VgI[3]; int VlO[3];
    #pragma unroll
    for (int i = 0; i < 3; i++) {
        int r = i * 4 + wv;
        int ksub = r & 3, kst = r >> 2;
        KgI[i] = Kb + (long)(ksub * 16 + l15) * ks + kst * 32 + quad * 8;
        KlO[i] = (ksub * 3 + kst) * 512;
        int nt = r >> 1, t2 = r & 1;
        VgI[i] = Vb + (long)(nt * 16 + l15) * 2048 + t2 * 32 + quad * 8;
        VlO[i] = r * 512;
    }

    // prologue: prefetch iter 0 into buffer 0
    #pragma unroll
    for (int i = 0; i < 3; i++) {
        load16(KgI[i], &Ks[0][0] + KlO[i]);
        load16(VgI[i], &Vs[0][0] + VlO[i]);
    }

    for (int it = 0; it < 8; it++) {
        __syncthreads();   // drains DMA for buf[it&1]; all waves past reads of buf[nxt]
        int cur = it & 1, nxt = cur ^ 1;
        if (it + 1 < 8) {
            int j = (it + 1) * 64;
            #pragma unroll
            for (int i = 0; i < 3; i++) {
                load16(KgI[i] + (long)j * ks, &Ks[nxt][0] + KlO[i]);
                load16(VgI[i] + j, &Vs[nxt][0] + VlO[i]);
            }
        }

        // scores: shared K frag feeds both Q-subtiles
        f32x4 sc[2][4];
        #pragma unroll
        for (int g = 0; g < 2; g++)
            #pragma unroll
            for (int s = 0; s < 4; s++) sc[g][s] = (f32x4){0.f, 0.f, 0.f, 0.f};
        #pragma unroll
        for (int s = 0; s < 4; s++)
            #pragma unroll
            for (int t = 0; t < 3; t++) {
                u16x8 kf = *(const u16x8*)(&Ks[cur][0] + (s * 3 + t) * 512 + lane * 8);
                sc[0][s] = __builtin_amdgcn_mfma_f32_16x16x32_bf16(as_bf(qf[0][t]), as_bf(kf), sc[0][s], 0, 0, 0);
                sc[1][s] = __builtin_amdgcn_mfma_f32_16x16x32_bf16(as_bf(qf[1][t]), as_bf(kf), sc[1][s], 0, 0, 0);
            }

        // p = exp(s*scale); accumulate sums; write P (C-layout -> A-frag LDS, per wave+subtile)
        #pragma unroll
        for (int g = 0; g < 2; g++)
            #pragma unroll
            for (int s = 0; s < 4; s++) {
                int base = (s >> 1) * 544 + ((((s & 1) << 1) | (l15 >> 3))) * 136 + (l15 & 7);
                #pragma unroll
                for (int r = 0; r < 4; r++) {
                    float p = __expf(sc[g][s][r] * SCALE);
                    rs[g][r] += p;
                    Ps[wv][g][base + (quad * 4 + r) * 8] = f2bf(p);
                }
            }

        // PV: shared V frag feeds both subtiles
        #pragma unroll
        for (int t2 = 0; t2 < 2; t2++) {
            u16x8 pf0 = *(const u16x8*)(&Ps[wv][0][0] + t2 * 544 + quad * 136 + l15 * 8);
            u16x8 pf1 = *(const u16x8*)(&Ps[wv][1][0] + t2 * 544 + quad * 136 + l15 * 8);
            #pragma unroll
            for (int nt = 0; nt < 6; nt++) {
                u16x8 vf = *(const u16x8*)(&Vs[cur][0] + (nt * 2 + t2) * 512 + lane * 8);
                o[0][nt] = __builtin_amdgcn_mfma_f32_16x16x32_bf16(as_bf(pf0), as_bf(vf), o[0][nt], 0, 0, 0);
                o[1][nt] = __builtin_amdgcn_mfma_f32_16x16x32_bf16(as_bf(pf1), as_bf(vf), o[1][nt], 0, 0, 0);
            }
        }
    }

    #pragma unroll
    for (int off = 1; off < 16; off <<= 1)
        #pragma unroll
        for (int g = 0; g < 2; g++)
            #pragma unroll
            for (int r = 0; r < 4; r++) rs[g][r] += __shfl_xor(rs[g][r], off);

    #pragma unroll
    for (int g = 0; g < 2; g++) {
        float* Pob = Po + ((long)(split * 8 + bh) * 2048 + q0 + g * 16) * 96;
        #pragma unroll
        for (int nt = 0; nt < 6; nt++)
            #pragma unroll
            for (int r = 0; r < 4; r++)
                Pob[(long)(quad * 4 + r) * 96 + nt * 16 + l15] = o[g][nt][r];
        if (l15 == 0) {
            long mb = (long)(split * 8 + bh) * 2048 + q0 + g * 16 + quad * 4;
            #pragma unroll
            for (int r = 0; r < 4; r++) Pl[mb + r] = rs[g][r];
        }
    }
}

// ---------------- combine 4 key-split partials -> Z (bf16, gate/l applied) ----------------
__global__ __launch_bounds__(256)
void attn_combine(const float* __restrict__ Po, const float* __restrict__ Pl,
                  const float* __restrict__ gates, u16* __restrict__ Z) {
    int bh = blockIdx.y, b = bh >> 2, h = bh & 3;
    int tid = threadIdx.x;
    int rl = tid >> 2, part = tid & 3;
    int row = blockIdx.x * 64 + rl;
    long rbase = (long)bh * 2048 + row;

    float L = 0.f;
    #pragma unroll
    for (int s = 0; s < 4; s++) L += Pl[s * 16384 + rbase];
    float g = gates ? gates[bh] : 1.f;
    float sc = g / L;

    u16* Zr = Z + ((long)(b * 2048) + row) * 384 + h * 96 + part * 24;
    #pragma unroll
    for (int i = 0; i < 24; i += 4) {
        f32x4 acc = (f32x4){0.f, 0.f, 0.f, 0.f};
        #pragma unroll
        for (int s = 0; s < 4; s++) {
            f32x4 v = *(const f32x4*)(Po + ((long)s * 16384 + rbase) * 96 + part * 24 + i);
            #pragma unroll
            for (int e = 0; e < 4; e++) acc[e] += v[e];
        }
        u16x4 ov;
        #pragma unroll
        for (int e = 0; e < 4; e++) ov[e] = f2bf(acc[e] * sc);
        *(u16x4*)(Zr + i) = ov;
    }
}

// ---------------- Launch ----------------
extern "C" void kernel_launch(void* const* d_in, const int* in_sizes, int n_in,
                              void* d_out, int out_size, void* d_ws, size_t ws_size,
                              hipStream_t stream) {
    const float* x    = (const float*)d_in[0];
    const float* mem  = (const float*)d_in[1];
    const float* mc   = (const float*)d_in[2];
    const int*   aidx = (const int*)d_in[3];
    const float* cWq = (const float*)d_in[4],  *cbq = (const float*)d_in[5];
    const float* cWk = (const float*)d_in[6],  *cbk = (const float*)d_in[7];
    const float* cWv = (const float*)d_in[8],  *cbv = (const float*)d_in[9];
    const float* cWo = (const float*)d_in[10], *cbo = (const float*)d_in[11];
    const float* sWq = (const float*)d_in[12], *sbq = (const float*)d_in[13];
    const float* sWk = (const float*)d_in[14], *sbk = (const float*)d_in[15];
    const float* sWv = (const float*)d_in[16], *sbv = (const float*)d_in[17];
    const float* sWo = (const float*)d_in[18], *sbo = (const float*)d_in[19];
    const float* gW  = (const float*)d_in[20], *gb  = (const float*)d_in[21];
    const float* f1W = (const float*)d_in[22], *f1b = (const float*)d_in[23];
    const float* f2W = (const float*)d_in[24], *f2b = (const float*)d_in[25];
    const float* adA = (const float*)d_in[26], *adB = (const float*)d_in[27];
    const float* ln1g = (const float*)d_in[28], *ln1b = (const float*)d_in[29];
    const float* ln2g = (const float*)d_in[30], *ln2b = (const float*)d_in[31];
    const float* ln3g = (const float*)d_in[32], *ln3b = (const float*)d_in[33];

    // ---- workspace layout ----
    u16* p = (u16*)d_ws;
    u16* H      = p; p += (size_t)NR_ * 384;
    u16* bufQ   = p; p += (size_t)NR_ * 384;
    u16* bufKV  = p; p += (size_t)NR_ * 768;
    u16* bufQKV = p; p += (size_t)NR_ * 1152;
    u16* Vt     = p; p += (size_t)B_ * 384 * 2048;
    u16* Zb     = p; p += (size_t)NR_ * 384;
    u16* F      = p; p += (size_t)NR_ * 1536;
    u16* Tl     = p; p += (size_t)NR_ * 16;
    u16* memb   = p; p += (size_t)NR_ * 384;
    u16* Wq_c   = p; p += 147456;
    u16* Wkv_c  = p; p += 294912;
    u16* Wco    = p; p += 147456;
    u16* Wqkv_s = p; p += 442368;
    u16* Wso    = p; p += 147456;
    u16* Wf1    = p; p += 589824;
    u16* Wf2    = p; p += 589824;
    u16* WadA   = p; p += 24576;
    u16* WadB   = p; p += 24576;
    float* fp = (float*)p;
    float* X1 = fp;     fp += (size_t)NR_ * 384;
    float* X2 = fp;     fp += (size_t)NR_ * 384;
    float* Po = fp;     fp += (size_t)4 * 8 * 2048 * 96;
    float* Pl = fp;     fp += (size_t)4 * 8 * 2048;
    float* bkv_c  = fp; fp += 768;
    float* bqkv_s = fp; fp += 1152;
    float* gbuf   = fp; fp += 8;

    // ---- fused setup ----
    setup_kernel<<<dim3(96, 14), 256, 0, stream>>>(
        cWq, cWk, cWv, cWo, sWq, sWk, sWv, sWo, f1W, f2W, adA, adB, mem,
        Wq_c, Wkv_c, Wco, Wqkv_s, Wso, Wf1, Wf2, WadA, WadB, memb,
        cbk, cbv, sbq, sbk, sbv, bkv_c, bqkv_s, mc, gW, gb, gbuf);

    const float* nf = nullptr;
    const u16* nu = nullptr;
    // --- cross-attention ---
    ln_kernel<<<NR_, 384, 0, stream>>>(x, ln1g, ln1b, H);
    gemm_pipe<0, true, false, false><<<dim3(6, 64), 256, 0, stream>>>(H, Wq_c, cbq, nf, bufQ, 384, 384, nullptr, 0, nu, nu, nullptr);
    gemm_pipe<0, true, true, false><<<dim3(12, 64), 256, 0, stream>>>(memb, Wkv_c, bkv_c, nf, bufKV, 768, 384, Vt, 384, nu, nu, nullptr);
    attn_mfma<<<dim3(16, 8, 4), 256, 0, stream>>>(bufQ, 384, bufKV, 768, Vt, Po, Pl);
    attn_combine<<<dim3(32, 8), 256, 0, stream>>>(Po, Pl, nullptr, Zb);
    gemm_pipe<0, false, false, false><<<dim3(6, 64), 256, 0, stream>>>(Zb, Wco, cbo, x, X1, 384, 384, nullptr, 0, nu, nu, nullptr);

    // --- motif-gated self-attention ---
    ln_kernel<<<NR_, 384, 0, stream>>>(X1, ln2g, ln2b, H);
    gemm_pipe<0, true, true, false><<<dim3(18, 64), 256, 0, stream>>>(H, Wqkv_s, bqkv_s, nf, bufQKV, 1152, 384, Vt, 768, nu, nu, nullptr);
    attn_mfma<<<dim3(16, 8, 4), 256, 0, stream>>>(bufQKV, 1152, bufQKV + 384, 1152, Vt, Po, Pl);
    attn_combine<<<dim3(32, 8), 256, 0, stream>>>(Po, Pl, gbuf, Zb);
    gemm_pipe<0, false, false, false><<<dim3(6, 64), 256, 0, stream>>>(Zb, Wso, sbo, X1, X2, 384, 384, nullptr, 0, nu, nu, nullptr);

    // --- FFN + LoRA (LoRA-B fused into f2 epilogue) ---
    ln_kernel<<<NR_, 384, 0, stream>>>(X2, ln3g, ln3b, H);
    gemm_pipe<1, true, false, false><<<dim3(24, 64), 256, 0, stream>>>(H, Wf1, f1b, nf, F, 1536, 384, nullptr, 0, nu, nu, nullptr);
    gemm_small<0, true><<<dim3(1, 64), 256, 0, stream>>>(H, WadA, nullptr, nf, Tl, NR_, 16, 384, aidx, R_ * D_);
    gemm_pipe<0, false, false, true><<<dim3(6, 64), 256, 0, stream>>>(F, Wf2, f2b, X2, d_out, 384, 1536, nullptr, 0, Tl, WadB, aidx);
}

// Round 9
// 355.134 us; speedup vs baseline: 8.8658x; 1.0464x over previous
//
#include <hip/hip_runtime.h>
#include <hip/hip_bf16.h>
#include <math.h>

// Problem constants
#define B_   2
#define T_   2048
#define M_   2048
#define D_   384
#define H_   4
#define DH_  96
#define NM_  8
#define DF_  1536
#define R_   16
#define NR_  4096   // B*T = B*M rows

typedef unsigned short u16;
typedef u16    u16x8  __attribute__((ext_vector_type(8)));
typedef u16    u16x4  __attribute__((ext_vector_type(4)));
typedef __bf16 bf16x8 __attribute__((ext_vector_type(8)));
typedef float  f32x4  __attribute__((ext_vector_type(4)));

union V8 { u16x8 u; bf16x8 b; };
__device__ __forceinline__ bf16x8 as_bf(u16x8 x) { V8 v; v.u = x; return v.b; }

__device__ __forceinline__ u16 f2bf(float f) {
    unsigned u = __float_as_uint(f);
    unsigned r = (u + 0x7fffu + ((u >> 16) & 1u)) >> 16;
    return (u16)r;
}
__device__ __forceinline__ float bf2f(u16 u) {
    return __uint_as_float(((unsigned)u) << 16);
}

// async global->LDS: 16B per lane, dest = wave-uniform base + lane*16
__device__ __forceinline__ void load16(const u16* g, u16* l) {
    __builtin_amdgcn_global_load_lds(
        (const __attribute__((address_space(1))) void*)g,
        (__attribute__((address_space(3))) void*)l, 16, 0, 0);
}

// ---------------- fused setup: weight converts + bias pack + gates ----------------
__global__ __launch_bounds__(256)
void setup_kernel(const float* cWq, const float* cWk, const float* cWv, const float* cWo,
                  const float* sWq, const float* sWk, const float* sWv, const float* sWo,
                  const float* f1W, const float* f2W, const float* adA, const float* adB,
                  const float* mem,
                  u16* Wqkv_c, u16* Wco, u16* Wqkv_s, u16* Wso,
                  u16* Wf1, u16* Wf2, u16* WadA, u16* WadB, u16* memb,
                  const float* cbq, const float* cbk, const float* cbv,
                  const float* sbq, const float* sbk, const float* sbv,
                  float* bqkv_c, float* bqkv_s,
                  const float* mc, const float* gW, const float* gb, float* gates) {
    int seg = blockIdx.y;
    if (seg == 13) {
        for (int i = blockIdx.x * 256 + threadIdx.x; i < 2312; i += gridDim.x * 256) {
            if (i < 1152) {
                bqkv_c[i] = (i < 384) ? cbq[i] : (i < 768 ? cbk[i - 384] : cbv[i - 768]);
            } else if (i < 2304) {
                int j = i - 1152;
                bqkv_s[j] = (j < 384) ? sbq[j] : (j < 768 ? sbk[j - 384] : sbv[j - 768]);
            } else {
                int k = i - 2304;  // 0..7
                int b = k / H_, h = k % H_;
                float s = gb[h];
                for (int n = 0; n < NM_; n++)
                    s += mc[b * NM_ + n] * gW[h * NM_ + n];
                gates[k] = 1.f / (1.f + __expf(-s));
            }
        }
        return;
    }
    const float* s; u16* d; int n;
    switch (seg) {
        case 0:  s = cWq; d = Wqkv_c;           n = 147456; break;
        case 1:  s = cWk; d = Wqkv_c + 147456;  n = 147456; break;
        case 2:  s = cWv; d = Wqkv_c + 294912;  n = 147456; break;
        case 3:  s = cWo; d = Wco;              n = 147456; break;
        case 4:  s = sWq; d = Wqkv_s;           n = 147456; break;
        case 5:  s = sWk; d = Wqkv_s + 147456;  n = 147456; break;
        case 6:  s = sWv; d = Wqkv_s + 294912;  n = 147456; break;
        case 7:  s = sWo; d = Wso;              n = 147456; break;
        case 8:  s = f1W; d = Wf1;              n = 589824; break;
        case 9:  s = f2W; d = Wf2;              n = 589824; break;
        case 10: s = adA; d = WadA;             n = 24576;  break;
        case 11: s = adB; d = WadB;             n = 24576;  break;
        default: s = mem; d = memb;             n = 1572864; break;
    }
    for (int i = blockIdx.x * 256 + threadIdx.x; i < n; i += gridDim.x * 256)
        d[i] = f2bf(s[i]);
}

// ---------------- LayerNorm: fp32 in, bf16 out ----------------
__global__ __launch_bounds__(384)
void ln_kernel(const float* __restrict__ x, const float* __restrict__ g,
               const float* __restrict__ b, u16* __restrict__ out) {
    __shared__ float sm[8];
    int row = blockIdx.x;
    int t = threadIdx.x;
    float v = x[(long)row * D_ + t];

    float s = v;
    for (int o = 32; o > 0; o >>= 1) s += __shfl_down(s, o);
    if ((t & 63) == 0) sm[t >> 6] = s;
    __syncthreads();
    float mu = 0.f;
    for (int i = 0; i < 6; i++) mu += sm[i];
    mu *= (1.f / D_);
    __syncthreads();

    float d = v - mu;
    s = d * d;
    for (int o = 32; o > 0; o >>= 1) s += __shfl_down(s, o);
    if ((t & 63) == 0) sm[t >> 6] = s;
    __syncthreads();
    float var = 0.f;
    for (int i = 0; i < 6; i++) var += sm[i];
    var *= (1.f / D_);

    float r = rsqrtf(var + 1e-5f);
    out[(long)row * D_ + t] = f2bf(d * r * g[t] + b[t]);
}

// ---------------- unified pipelined MFMA GEMM ----------------
// MT: m-tiles per wave (2 -> 64-row block; 1 -> 32-row block). BK=64, dbuf, 1 barrier/iter.
// A-switch: blocks with bn < aswitch read A0, else A1.
// VT: cols >= vtbase written transposed to Vt[B][384][2048].
// LORA: += Tl @ adW[aidx]^T via extra MFMA. LORAA: block col NC/64 computes Tl = A @ adW[aidx]^T.
template<int MT, int ACT, bool OBF, bool VT, bool LORA, bool LORAA>
__global__ __launch_bounds__(256)
void gemm_uni(const u16* __restrict__ A0, const u16* __restrict__ A1, int aswitch,
              const u16* __restrict__ W, const float* __restrict__ bias,
              const float* __restrict__ res, void* __restrict__ Cout, int NC, int K,
              u16* __restrict__ Vt, int vtbase,
              const u16* __restrict__ Tl, const u16* __restrict__ adW,
              u16* __restrict__ TlOut, const int* __restrict__ aidx) {
    constexpr int NREG = 4 * MT + 8;
    constexpr int HALF = NREG * 512;
    __shared__ __align__(16) u16 S[2 * HALF];
    int tid = threadIdx.x, w = tid >> 6, lane = tid & 63;
    int l15 = lane & 15, quad = lane >> 4;
    int bm = blockIdx.y * (MT * 32), bn = blockIdx.x * 64;
    bool loraBlk = LORAA && (bn >= NC);

    const u16* Ap = (bn < aswitch) ? A0 : A1;
    const u16* Wb = W;
    if (LORAA && loraBlk) Wb = adW + (long)aidx[0] * 6144;

    const u16* GP[MT + 2];
    int LO[MT + 2];
    #pragma unroll
    for (int i = 0; i < MT + 2; i++) {
        int r = i * 4 + w;
        const u16* src;
        if (r < 4 * MT) {
            int mt = r >> 1, kc = r & 1;
            src = Ap + (long)(bm + mt * 16 + l15) * K + kc * 32 + quad * 8;
        } else {
            int rw = r - 4 * MT, nt = rw >> 1, kc = rw & 1;
            if (LORAA && loraBlk)
                src = Wb + (long)((nt * 16 + l15) & 15) * K + kc * 32 + quad * 8;
            else
                src = Wb + (long)(bn + nt * 16 + l15) * K + kc * 32 + quad * 8;
        }
        GP[i] = src;
        LO[i] = r * 512;
    }

    f32x4 acc[MT][2];
    #pragma unroll
    for (int s = 0; s < MT; s++)
        #pragma unroll
        for (int j = 0; j < 2; j++) acc[s][j] = (f32x4){0.f, 0.f, 0.f, 0.f};

    int niter = K >> 6;
    #pragma unroll
    for (int i = 0; i < MT + 2; i++) load16(GP[i], S + LO[i]);

    for (int it = 0; it < niter; it++) {
        __syncthreads();
        int cur = (it & 1) * HALF, nxt = HALF - cur;
        if (it + 1 < niter) {
            int k = (it + 1) << 6;
            #pragma unroll
            for (int i = 0; i < MT + 2; i++) load16(GP[i] + k, S + nxt + LO[i]);
        }
        #pragma unroll
        for (int kc = 0; kc < 2; kc++) {
            u16x8 af[MT], bfv[2];
            #pragma unroll
            for (int s = 0; s < MT; s++)
                af[s] = *(const u16x8*)(S + cur + (((w & 1) * MT + s) * 2 + kc) * 512 + lane * 8);
            #pragma unroll
            for (int j = 0; j < 2; j++)
                bfv[j] = *(const u16x8*)(S + cur + (4 * MT + (((w >> 1) * 2 + j) * 2 + kc)) * 512 + lane * 8);
            #pragma unroll
            for (int s = 0; s < MT; s++)
                #pragma unroll
                for (int j = 0; j < 2; j++)
                    acc[s][j] = __builtin_amdgcn_mfma_f32_16x16x32_bf16(
                        as_bf(af[s]), as_bf(bfv[j]), acc[s][j], 0, 0, 0);
        }
    }

    if (LORA) {
        long ao = (long)aidx[0] * 6144;
        u16x8 tlf[MT], adf[2];
        #pragma unroll
        for (int s = 0; s < MT; s++) {
            #pragma unroll
            for (int e = 0; e < 8; e++) tlf[s][e] = 0;
            if (quad < 2)
                tlf[s] = *(const u16x8*)(Tl + (long)(bm + ((w & 1) * MT + s) * 16 + l15) * 16 + quad * 8);
        }
        #pragma unroll
        for (int j = 0; j < 2; j++) {
            #pragma unroll
            for (int e = 0; e < 8; e++) adf[j][e] = 0;
            if (quad < 2)
                adf[j] = *(const u16x8*)(adW + ao + (long)(bn + ((w >> 1) * 2 + j) * 16 + l15) * 16 + quad * 8);
        }
        #pragma unroll
        for (int s = 0; s < MT; s++)
            #pragma unroll
            for (int j = 0; j < 2; j++)
                acc[s][j] = __builtin_amdgcn_mfma_f32_16x16x32_bf16(
                    as_bf(tlf[s]), as_bf(adf[j]), acc[s][j], 0, 0, 0);
    }

    #pragma unroll
    for (int mi = 0; mi < MT; mi++) {
        int mt = (w & 1) * MT + mi;
        int rowb = bm + mt * 16 + quad * 4;
        #pragma unroll
        for (int nj = 0; nj < 2; nj++) {
            int coll = ((w >> 1) * 2 + nj) * 16 + l15;
            int col = bn + coll;
            if (LORAA && loraBlk) {
                if (coll < 16) {
                    #pragma unroll
                    for (int r = 0; r < 4; r++)
                        TlOut[(long)(rowb + r) * 16 + coll] = f2bf(acc[mi][nj][r]);
                }
            } else {
                float bv = bias ? bias[col] : 0.f;
                if (VT && col >= vtbase) {
                    int vc = col - vtbase;
                    int b = rowb >> 11, rowl = rowb & 2047;
                    u16x4 ov;
                    #pragma unroll
                    for (int r = 0; r < 4; r++) ov[r] = f2bf(acc[mi][nj][r] + bv);
                    *(u16x4*)(Vt + ((long)b * 384 + vc) * 2048 + rowl) = ov;
                } else {
                    #pragma unroll
                    for (int r = 0; r < 4; r++) {
                        float v = acc[mi][nj][r] + bv;
                        if (ACT == 1) v = 0.5f * v * (1.f + erff(v * 0.70710678118654752f));
                        long idx = (long)(rowb + r) * NC + col;
                        if (res) v += res[idx];
                        if (OBF) ((u16*)Cout)[idx] = f2bf(v);
                        else     ((float*)Cout)[idx] = v;
                    }
                }
            }
        }
    }
}

// ---------------- Flash attention: 32 Q-rows/wave (2 subtiles), dbuf K/V, key-split x4 ----------------
__global__ __launch_bounds__(256)
void attn_mfma(const u16* __restrict__ Qg, int qs,
               const u16* __restrict__ Kg, int ks,
               const u16* __restrict__ Vt,
               u16* __restrict__ Po, float* __restrict__ Pl) {
    __shared__ __align__(16) u16 Ks[2][6144];
    __shared__ __align__(16) u16 Vs[2][6144];
    __shared__ __align__(16) u16 Ps[4][2][1088];
    const float SCALE = 0.10206207261596575f;  // 1/sqrt(96)

    int tid = threadIdx.x, wv = tid >> 6, lane = tid & 63;
    int l15 = lane & 15, quad = lane >> 4;
    int bh = blockIdx.y, b = bh >> 2, h = bh & 3;
    int split = blockIdx.z;
    int q0 = blockIdx.x * 128 + wv * 32;

    const u16* Qb = Qg + (long)(b * 2048 + q0) * qs + h * 96;
    const u16* Kb = Kg + (long)(b * 2048 + split * 512) * ks + h * 96;
    const u16* Vb = Vt + (long)(b * 384 + h * 96) * 2048 + split * 512;

    u16x8 qf[2][3];
    #pragma unroll
    for (int g = 0; g < 2; g++)
        #pragma unroll
        for (int t = 0; t < 3; t++)
            qf[g][t] = *(const u16x8*)(Qb + (long)(g * 16 + l15) * qs + t * 32 + quad * 8);

    f32x4 o[2][6];
    #pragma unroll
    for (int g = 0; g < 2; g++)
        #pragma unroll
        for (int i = 0; i < 6; i++) o[g][i] = (f32x4){0.f, 0.f, 0.f, 0.f};
    float rs[2][4] = {{0.f, 0.f, 0.f, 0.f}, {0.f, 0.f, 0.f, 0.f}};

    const u16* KgI[3]; int KlO[3]; const u16* VgI[3]; int VlO[3];
    #pragma unroll
    for (int i = 0; i < 3; i++) {
        int r = i * 4 + wv;
        int ksub = r & 3, kst = r >> 2;
        KgI[i] = Kb + (long)(ksub * 16 + l15) * ks + kst * 32 + quad * 8;
        KlO[i] = (ksub * 3 + kst) * 512;
        int nt = r >> 1, t2 = r & 1;
        VgI[i] = Vb + (long)(nt * 16 + l15) * 2048 + t2 * 32 + quad * 8;
        VlO[i] = r * 512;
    }

    #pragma unroll
    for (int i = 0; i < 3; i++) {
        load16(KgI[i], &Ks[0][0] + KlO[i]);
        load16(VgI[i], &Vs[0][0] + VlO[i]);
    }

    for (int it = 0; it < 8; it++) {
        __syncthreads();
        int cur = it & 1, nxt = cur ^ 1;
        if (it + 1 < 8) {
            int j = (it + 1) * 64;
            #pragma unroll
            for (int i = 0; i < 3; i++) {
                load16(KgI[i] + (long)j * ks, &Ks[nxt][0] + KlO[i]);
                load16(VgI[i] + j, &Vs[nxt][0] + VlO[i]);
            }
        }

        f32x4 sc[2][4];
        #pragma unroll
        for (int g = 0; g < 2; g++)
            #pragma unroll
            for (int s = 0; s < 4; s++) sc[g][s] = (f32x4){0.f, 0.f, 0.f, 0.f};
        #pragma unroll
        for (int s = 0; s < 4; s++)
            #pragma unroll
            for (int t = 0; t < 3; t++) {
                u16x8 kf = *(const u16x8*)(&Ks[cur][0] + (s * 3 + t) * 512 + lane * 8);
                sc[0][s] = __builtin_amdgcn_mfma_f32_16x16x32_bf16(as_bf(qf[0][t]), as_bf(kf), sc[0][s], 0, 0, 0);
                sc[1][s] = __builtin_amdgcn_mfma_f32_16x16x32_bf16(as_bf(qf[1][t]), as_bf(kf), sc[1][s], 0, 0, 0);
            }

        #pragma unroll
        for (int g = 0; g < 2; g++)
            #pragma unroll
            for (int s = 0; s < 4; s++) {
                int base = (s >> 1) * 544 + ((((s & 1) << 1) | (l15 >> 3))) * 136 + (l15 & 7);
                #pragma unroll
                for (int r = 0; r < 4; r++) {
                    float p = __expf(sc[g][s][r] * SCALE);
                    rs[g][r] += p;
                    Ps[wv][g][base + (quad * 4 + r) * 8] = f2bf(p);
                }
            }

        #pragma unroll
        for (int t2 = 0; t2 < 2; t2++) {
            u16x8 pf0 = *(const u16x8*)(&Ps[wv][0][0] + t2 * 544 + quad * 136 + l15 * 8);
            u16x8 pf1 = *(const u16x8*)(&Ps[wv][1][0] + t2 * 544 + quad * 136 + l15 * 8);
            #pragma unroll
            for (int nt = 0; nt < 6; nt++) {
                u16x8 vf = *(const u16x8*)(&Vs[cur][0] + (nt * 2 + t2) * 512 + lane * 8);
                o[0][nt] = __builtin_amdgcn_mfma_f32_16x16x32_bf16(as_bf(pf0), as_bf(vf), o[0][nt], 0, 0, 0);
                o[1][nt] = __builtin_amdgcn_mfma_f32_16x16x32_bf16(as_bf(pf1), as_bf(vf), o[1][nt], 0, 0, 0);
            }
        }
    }

    #pragma unroll
    for (int off = 1; off < 16; off <<= 1)
        #pragma unroll
        for (int g = 0; g < 2; g++)
            #pragma unroll
            for (int r = 0; r < 4; r++) rs[g][r] += __shfl_xor(rs[g][r], off);

    #pragma unroll
    for (int g = 0; g < 2; g++) {
        u16* Pob = Po + ((long)(split * 8 + bh) * 2048 + q0 + g * 16) * 96;
        #pragma unroll
        for (int nt = 0; nt < 6; nt++)
            #pragma unroll
            for (int r = 0; r < 4; r++)
                Pob[(long)(quad * 4 + r) * 96 + nt * 16 + l15] = f2bf(o[g][nt][r]);
        if (l15 == 0) {
            long mb = (long)(split * 8 + bh) * 2048 + q0 + g * 16 + quad * 4;
            #pragma unroll
            for (int r = 0; r < 4; r++) Pl[mb + r] = rs[g][r];
        }
    }
}

// ---------------- combine 4 key-split partials (bf16) -> Z (bf16, gate/l applied) ----------------
__global__ __launch_bounds__(256)
void attn_combine(const u16* __restrict__ Po, const float* __restrict__ Pl,
                  const float* __restrict__ gates, u16* __restrict__ Z) {
    int bh = blockIdx.y, b = bh >> 2, h = bh & 3;
    int tid = threadIdx.x;
    int rl = tid >> 2, part = tid & 3;
    int row = blockIdx.x * 64 + rl;
    long rbase = (long)bh * 2048 + row;

    float L = 0.f;
    #pragma unroll
    for (int s = 0; s < 4; s++) L += Pl[s * 16384 + rbase];
    float g = gates ? gates[bh] : 1.f;
    float sc = g / L;

    u16* Zr = Z + ((long)(b * 2048) + row) * 384 + h * 96 + part * 24;
    #pragma unroll
    for (int i = 0; i < 24; i += 4) {
        f32x4 acc = (f32x4){0.f, 0.f, 0.f, 0.f};
        #pragma unroll
        for (int s = 0; s < 4; s++) {
            u16x4 v = *(const u16x4*)(Po + ((long)s * 16384 + rbase) * 96 + part * 24 + i);
            #pragma unroll
            for (int e = 0; e < 4; e++) acc[e] += bf2f(v[e]);
        }
        u16x4 ov;
        #pragma unroll
        for (int e = 0; e < 4; e++) ov[e] = f2bf(acc[e] * sc);
        *(u16x4*)(Zr + i) = ov;
    }
}

// ---------------- Launch ----------------
extern "C" void kernel_launch(void* const* d_in, const int* in_sizes, int n_in,
                              void* d_out, int out_size, void* d_ws, size_t ws_size,
                              hipStream_t stream) {
    const float* x    = (const float*)d_in[0];
    const float* mem  = (const float*)d_in[1];
    const float* mc   = (const float*)d_in[2];
    const int*   aidx = (const int*)d_in[3];
    const float* cWq = (const float*)d_in[4],  *cbq = (const float*)d_in[5];
    const float* cWk = (const float*)d_in[6],  *cbk = (const float*)d_in[7];
    const float* cWv = (const float*)d_in[8],  *cbv = (const float*)d_in[9];
    const float* cWo = (const float*)d_in[10], *cbo = (const float*)d_in[11];
    const float* sWq = (const float*)d_in[12], *sbq = (const float*)d_in[13];
    const float* sWk = (const float*)d_in[14], *sbk = (const float*)d_in[15];
    const float* sWv = (const float*)d_in[16], *sbv = (const float*)d_in[17];
    const float* sWo = (const float*)d_in[18], *sbo = (const float*)d_in[19];
    const float* gW  = (const float*)d_in[20], *gb  = (const float*)d_in[21];
    const float* f1W = (const float*)d_in[22], *f1b = (const float*)d_in[23];
    const float* f2W = (const float*)d_in[24], *f2b = (const float*)d_in[25];
    const float* adA = (const float*)d_in[26], *adB = (const float*)d_in[27];
    const float* ln1g = (const float*)d_in[28], *ln1b = (const float*)d_in[29];
    const float* ln2g = (const float*)d_in[30], *ln2b = (const float*)d_in[31];
    const float* ln3g = (const float*)d_in[32], *ln3b = (const float*)d_in[33];

    // ---- workspace layout ----
    u16* p = (u16*)d_ws;
    u16* H      = p; p += (size_t)NR_ * 384;
    u16* bufQKV = p; p += (size_t)NR_ * 1152;
    u16* Vt     = p; p += (size_t)B_ * 384 * 2048;
    u16* Zb     = p; p += (size_t)NR_ * 384;
    u16* F      = p; p += (size_t)NR_ * 1536;
    u16* Tl     = p; p += (size_t)NR_ * 16;
    u16* memb   = p; p += (size_t)NR_ * 384;
    u16* Wqkv_c = p; p += 442368;
    u16* Wco    = p; p += 147456;
    u16* Wqkv_s = p; p += 442368;
    u16* Wso    = p; p += 147456;
    u16* Wf1    = p; p += 589824;
    u16* Wf2    = p; p += 589824;
    u16* WadA   = p; p += 24576;
    u16* WadB   = p; p += 24576;
    u16* Po     = p; p += (size_t)4 * 8 * 2048 * 96;
    p += ((size_t)p & 1);   // (no-op; keep alignment thinking explicit)
    float* fp = (float*)(((size_t)p + 3) & ~(size_t)3);
    float* X1 = fp;     fp += (size_t)NR_ * 384;
    float* X2 = fp;     fp += (size_t)NR_ * 384;
    float* Pl = fp;     fp += (size_t)4 * 8 * 2048;
    float* bqkv_c = fp; fp += 1152;
    float* bqkv_s = fp; fp += 1152;
    float* gbuf   = fp; fp += 8;

    // ---- fused setup ----
    setup_kernel<<<dim3(96, 14), 256, 0, stream>>>(
        cWq, cWk, cWv, cWo, sWq, sWk, sWv, sWo, f1W, f2W, adA, adB, mem,
        Wqkv_c, Wco, Wqkv_s, Wso, Wf1, Wf2, WadA, WadB, memb,
        cbq, cbk, cbv, sbq, sbk, sbv, bqkv_c, bqkv_s, mc, gW, gb, gbuf);

    const float* nf = nullptr;
    const u16* nu = nullptr;
    // --- cross-attention: merged QKV projection (Q from H, K/V from memb) ---
    ln_kernel<<<NR_, 384, 0, stream>>>(x, ln1g, ln1b, H);
    gemm_uni<2, 0, true, true, false, false><<<dim3(18, 64), 256, 0, stream>>>(
        H, memb, 384, Wqkv_c, bqkv_c, nf, bufQKV, 1152, 384, Vt, 768, nu, nu, nullptr, nullptr);
    attn_mfma<<<dim3(16, 8, 4), 256, 0, stream>>>(bufQKV, 1152, bufQKV + 384, 1152, Vt, Po, Pl);
    attn_combine<<<dim3(32, 8), 256, 0, stream>>>(Po, Pl, nullptr, Zb);
    gemm_uni<1, 0, false, false, false, false><<<dim3(6, 128), 256, 0, stream>>>(
        Zb, Zb, 0, Wco, cbo, x, X1, 384, 384, nullptr, 0, nu, nu, nullptr, nullptr);

    // --- motif-gated self-attention ---
    ln_kernel<<<NR_, 384, 0, stream>>>(X1, ln2g, ln2b, H);
    gemm_uni<2, 0, true, true, false, false><<<dim3(18, 64), 256, 0, stream>>>(
        H, H, 0, Wqkv_s, bqkv_s, nf, bufQKV, 1152, 384, Vt, 768, nu, nu, nullptr, nullptr);
    attn_mfma<<<dim3(16, 8, 4), 256, 0, stream>>>(bufQKV, 1152, bufQKV + 384, 1152, Vt, Po, Pl);
    attn_combine<<<dim3(32, 8), 256, 0, stream>>>(Po, Pl, gbuf, Zb);
    gemm_uni<1, 0, false, false, false, false><<<dim3(6, 128), 256, 0, stream>>>(
        Zb, Zb, 0, Wso, sbo, X1, X2, 384, 384, nullptr, 0, nu, nu, nullptr, nullptr);

    // --- FFN + LoRA (adA fused into f1 as 25th block-col; loraB fused into f2 epilogue) ---
    ln_kernel<<<NR_, 384, 0, stream>>>(X2, ln3g, ln3b, H);
    gemm_uni<2, 1, true, false, false, true><<<dim3(25, 64), 256, 0, stream>>>(
        H, H, 0, Wf1, f1b, nf, F, 1536, 384, nullptr, 0, nu, WadA, Tl, aidx);
    gemm_uni<1, 0, false, false, true, false><<<dim3(6, 128), 256, 0, stream>>>(
        F, F, 0, Wf2, f2b, X2, d_out, 384, 1536, nullptr, 0, Tl, WadB, nullptr, aidx);
}